// Round 13
// baseline (77.745 us; speedup 1.0000x reference)
//
#include <hip/hip_runtime.h>

// Problem constants
#define B_N   2
#define H_LR  64
#define W_LR  64
#define HUP   128
#define WUP   128
#define GRP   4
#define NPT   9
#define EMB   32
#define CGRP  64
#define KIN   256
#define GE    128
#define NOFF  288

typedef __attribute__((ext_vector_type(8))) short short8v;
typedef _Float16 half8v __attribute__((ext_vector_type(8)));
typedef __attribute__((ext_vector_type(4))) float f32x4;

__device__ __forceinline__ ushort f2bf(float f) {
    unsigned u = __float_as_uint(f);
    u += 0x7FFFu + ((u >> 16) & 1u);
    return (ushort)(u >> 16);
}
__device__ __forceinline__ float bf2f(ushort h) {
    return __uint_as_float(((unsigned)h) << 16);
}
__device__ __forceinline__ ushort f2h(float f) {
    _Float16 h = (_Float16)f;
    return __builtin_bit_cast(ushort, h);
}
__device__ __forceinline__ float h2f(ushort u) {
    _Float16 h = __builtin_bit_cast(_Float16, u);
    return (float)h;
}

// ---------------------------------------------------------------------------
// Merged bf16 MFMA GEMM for both 1x1 convs, register-prefetch pipelined.
// (unchanged from round 12)
// ---------------------------------------------------------------------------
__global__ __launch_bounds__(256, 4) void mfma_gemm(
    const float* __restrict__ y, const float* __restrict__ x,
    const float* __restrict__ Wq, const float* __restrict__ Wk,
    const float* __restrict__ Woff,
    const float* __restrict__ bq, const float* __restrict__ bk,
    const float* __restrict__ boff,
    ushort* __restrict__ qbf, ushort* __restrict__ kbf,
    float* __restrict__ offw)
{
    __shared__ __align__(16) ushort sY[64][68];
    __shared__ __align__(16) ushort sB[128][72];

    int bid = blockIdx.x;
    const float* SRC; const float* ba; const float* bb;
    ushort* OBF; float* OFP;
    int M, m0, n0, b;
    bool isQ = (bid < 512);
    if (isQ) {
        int mt = bid & 255; b = bid >> 8;
        SRC = y; ba = bq; bb = nullptr; OBF = qbf; OFP = nullptr;
        M = 16384; m0 = mt * 64; n0 = 0;
    } else {
        int r = bid - 512;
        int mt = r & 63, nt2 = (r >> 6) & 3; b = r >> 8;
        SRC = x; ba = bk; bb = boff; OBF = kbf; OFP = offw;
        M = 4096; m0 = mt * 64; n0 = nt2 * 128;
    }

    int tid = threadIdx.x;
    int lane = tid & 63;
    int wv = tid >> 6, wm = wv >> 1, wn = wv & 1;
    int il = lane & 15, g4 = lane >> 4;
    int st_m4 = tid & 15, st_c = tid >> 4;
    int st_c8 = tid & 7,  st_n = tid >> 3;

    const float* wrowp[4];
#pragma unroll
    for (int i = 0; i < 4; ++i) {
        int n = n0 + st_n + i * 32;
        if (isQ)            wrowp[i] = Wq  + (size_t)n * KIN;
        else if (n < GE)    wrowp[i] = Wk  + (size_t)n * KIN;
        else if (n < GE + NOFF) wrowp[i] = Woff + (size_t)(n - GE) * KIN;
        else                wrowp[i] = nullptr;
    }

    f32x4 acc[2][4];
#pragma unroll
    for (int i = 0; i < 2; ++i)
#pragma unroll
        for (int j = 0; j < 4; ++j) { f32x4 z = {0.f,0.f,0.f,0.f}; acc[i][j] = z; }

    const float* src_b = SRC + (size_t)b * KIN * M;

    float4 ra[4]; short8v rb[4];
#pragma unroll
    for (int i = 0; i < 4; ++i)
        ra[i] = *(const float4*)&src_b[(size_t)(st_c + i * 16) * M + m0 + st_m4 * 4];
#pragma unroll
    for (int i = 0; i < 4; ++i) {
        short8v t = {0,0,0,0,0,0,0,0};
        if (wrowp[i]) {
            float4 a = *(const float4*)&wrowp[i][st_c8 * 8];
            float4 c = *(const float4*)&wrowp[i][st_c8 * 8 + 4];
            t[0]=(short)f2bf(a.x); t[1]=(short)f2bf(a.y); t[2]=(short)f2bf(a.z); t[3]=(short)f2bf(a.w);
            t[4]=(short)f2bf(c.x); t[5]=(short)f2bf(c.y); t[6]=(short)f2bf(c.z); t[7]=(short)f2bf(c.w);
        }
        rb[i] = t;
    }

    for (int ks = 0; ks < 4; ++ks) {
#pragma unroll
        for (int i = 0; i < 4; ++i) {
            ushort4 h;
            h.x = f2bf(ra[i].x); h.y = f2bf(ra[i].y);
            h.z = f2bf(ra[i].z); h.w = f2bf(ra[i].w);
            *(ushort4*)&sY[st_c + i * 16][st_m4 * 4] = h;
            *(short8v*)&sB[st_n + i * 32][st_c8 * 8] = rb[i];
        }
        __syncthreads();
        if (ks < 3) {
            int k0 = (ks + 1) * 64;
#pragma unroll
            for (int i = 0; i < 4; ++i)
                ra[i] = *(const float4*)&src_b[(size_t)(k0 + st_c + i * 16) * M + m0 + st_m4 * 4];
#pragma unroll
            for (int i = 0; i < 4; ++i) {
                short8v t = {0,0,0,0,0,0,0,0};
                if (wrowp[i]) {
                    float4 a = *(const float4*)&wrowp[i][k0 + st_c8 * 8];
                    float4 c = *(const float4*)&wrowp[i][k0 + st_c8 * 8 + 4];
                    t[0]=(short)f2bf(a.x); t[1]=(short)f2bf(a.y); t[2]=(short)f2bf(a.z); t[3]=(short)f2bf(a.w);
                    t[4]=(short)f2bf(c.x); t[5]=(short)f2bf(c.y); t[6]=(short)f2bf(c.z); t[7]=(short)f2bf(c.w);
                }
                rb[i] = t;
            }
        }
#pragma unroll
        for (int kc = 0; kc < 2; ++kc) {
            int kb = kc * 32 + g4 * 8;
            short8v af[2], bfr[4];
#pragma unroll
            for (int mf = 0; mf < 2; ++mf) {
                int m = wm * 32 + mf * 16 + il;
                short8v t;
#pragma unroll
                for (int j = 0; j < 8; ++j) t[j] = (short)sY[kb + j][m];
                af[mf] = t;
            }
#pragma unroll
            for (int nf = 0; nf < 4; ++nf)
                bfr[nf] = *(const short8v*)&sB[wn * 64 + nf * 16 + il][kb];
#pragma unroll
            for (int mf = 0; mf < 2; ++mf)
#pragma unroll
                for (int nf = 0; nf < 4; ++nf)
                    acc[mf][nf] = __builtin_amdgcn_mfma_f32_16x16x32_bf16(
                        af[mf], bfr[nf], acc[mf][nf], 0, 0, 0);
        }
        __syncthreads();
    }

#pragma unroll
    for (int mf = 0; mf < 2; ++mf) {
#pragma unroll
        for (int r = 0; r < 4; ++r) {
            int m = m0 + wm * 32 + mf * 16 + g4 * 4 + r;
            size_t row = (size_t)b * M + m;
#pragma unroll
            for (int nf = 0; nf < 4; ++nf) {
                int n = n0 + wn * 64 + nf * 16 + il;
                float v = acc[mf][nf][r];
                if (n < GE) {
                    OBF[row * 128 + n] = f2bf(v + ba[n]);
                } else {
                    int no = n - GE;
                    if (no < NOFF) OFP[row * 288 + no] = v + bb[no];
                }
            }
        }
    }
}

// ---------------------------------------------------------------------------
// Fused deformable attention via per-block dense MFMA GEMMs.
// r11 structure + parallel atomic W-build: W is fp32 [64][68] (aliases the
// post-P2-dead sK+sQ+S region); P4 = 256 threads (corner, px) doing
// fire-and-forget ds_add_f32 — no dependent RMW chain, no wave0 serialization.
// ---------------------------------------------------------------------------
#define RROWS 6
#define RCOLS 11
#define RPX   66

__global__ __launch_bounds__(256, 4) void deform_kernel(
    const ushort* __restrict__ qbf,  // [B, 16384, 128] bf16 pixel-major
    const ushort* __restrict__ kbf,  // [B, 4096, 128] bf16 pixel-major
    const float* __restrict__ offw,  // [B, 4096, 288] fp32 pixel-major
    const float* __restrict__ x,     // [B, 256, 64, 64] channel-major (input)
    float* __restrict__ out)         // [B, 256, 128, 128]
{
    __shared__ __align__(16) char smem[36272];
    ushort (*sXt)[72] = (ushort(*)[72])(smem);            // [0,9216)     x region fp16
    ushort (*sK)[40]  = (ushort(*)[40])(smem + 9216);     // [9216,14496) k region bf16
    ushort (*sQ)[40]  = (ushort(*)[40])(smem + 14496);    // [14496,19616) q bf16
    ushort (*sS)[72]  = (ushort(*)[72])(smem + 19616);    // [19616,28832) S fp16
    float* sOff       = (float*)(smem + 19616);           // [16][72] fp32 (pre-S alias)
    uint*  sGt        = (uint*)(smem + 28832);            // [28832,31136)
    int*   sGz        = (int*)(smem + 31136);             // [31136,33440)
    float* sAttn      = (float*)(smem + 33440);           // [33440,35744)
    int*   sFB        = (int*)(smem + 35744);             // [35744,36260)
    float (*sW)[68]   = (float(*)[68])(smem + 9216);      // [9216,26624) W fp32 (post-P2 alias)

    int bx = blockIdx.x;
    int tw = bx & 7, th = (bx >> 3) & 31, g = (bx >> 8) & 3, b = bx >> 10;
    int tid = threadIdx.x;
    int wv_ = tid >> 6, lane = tid & 63;
    int row = lane & 15, kb8 = lane >> 4;

    const int ry0 = th * 2 - 2, rx0 = tw * 8 - 1;

    // ---------------- P0a: all staging (coalesced) -------------------------
    if (tid == 0) sFB[0] = 0;
    // x region -> fp16, pair-packed u32 stores
    for (int s = tid; s < 384; s += 256) {
        int gy = s % 6, ch = s / 6;
        int gyg = min(max(ry0 + gy, 0), 63);
        const float* xr = x + ((size_t)b * 256 + g * CGRP + ch) * 4096 + gyg * 64;
        float v[11];
        if (tw >= 1 && tw <= 6) {
            int a0 = rx0 - 3;                    // 16B-aligned, in-bounds
            float tmp[16];
#pragma unroll
            for (int t4 = 0; t4 < 4; ++t4) {
                float4 f = *(const float4*)&xr[a0 + t4 * 4];
                tmp[t4*4+0] = f.x; tmp[t4*4+1] = f.y; tmp[t4*4+2] = f.z; tmp[t4*4+3] = f.w;
            }
#pragma unroll
            for (int qx = 0; qx < RCOLS; ++qx) v[qx] = tmp[qx + 3];
        } else {
#pragma unroll
            for (int qx = 0; qx < RCOLS; ++qx) {
                int gxg = min(max(rx0 + qx, 0), 63);
                v[qx] = xr[gxg];
            }
        }
        ushort* dst = &sXt[ch][0];
        int c0 = gy * RCOLS;
        if (c0 & 1) {
            dst[c0] = f2h(v[0]);
#pragma unroll
            for (int j = 0; j < 5; ++j)
                *(uint*)&dst[c0 + 1 + 2*j] =
                    (uint)f2h(v[1 + 2*j]) | ((uint)f2h(v[2 + 2*j]) << 16);
        } else {
#pragma unroll
            for (int j = 0; j < 5; ++j)
                *(uint*)&dst[c0 + 2*j] =
                    (uint)f2h(v[2*j]) | ((uint)f2h(v[1 + 2*j]) << 16);
            dst[c0 + 10] = f2h(v[10]);
        }
    }
    // k region bf16
    for (int i = tid; i < 264; i += 256) {
        int rp = i >> 2, c4 = i & 3;
        int qy = rp / RCOLS, qx = rp - qy * RCOLS;
        int gy = min(max(ry0 + qy, 0), 63), gx = min(max(rx0 + qx, 0), 63);
        *(short8v*)&sK[rp][c4 * 8] =
            *(const short8v*)&kbf[((size_t)b * 4096 + gy * 64 + gx) * 128 +
                                  g * EMB + c4 * 8];
    }
    // q bf16
    {
        int px = tid >> 2, c4 = tid & 3;
        int hup = th * 4 + (px >> 4), wup = tw * 16 + (px & 15);
        *(short8v*)&sQ[px][c4 * 8] =
            *(const short8v*)&qbf[((size_t)b * 16384 + hup * 128 + wup) * 128 +
                                  g * EMB + c4 * 8];
    }
    // offsets (coalesced float4) -> sOff
    for (int i = tid; i < 288; i += 256) {
        int lr = i / 18, f4 = i - (i / 18) * 18;
        int yy = th * 2 + (lr >> 3), xx = tw * 8 + (lr & 7);
        *(float4*)&sOff[lr * 72 + f4 * 4] =
            *(const float4*)&offw[((size_t)b * 4096 + yy * 64 + xx) * 288 +
                                  g * 72 + f4 * 4];
    }
    __syncthreads();

    // ---------------- P0b: S-GEMM (to regs) + geometry ---------------------
    f32x4 sreg[5];
    {
        short8v a = *(const short8v*)&sQ[wv_ * 16 + row][kb8 * 8];
#pragma unroll
        for (int nt = 0; nt < 5; ++nt) {
            int rr = nt * 16 + row; if (rr > 65) rr = 65;   // tail clamp
            short8v bf = *(const short8v*)&sK[rr][kb8 * 8];
            f32x4 z = {0.f, 0.f, 0.f, 0.f};
            sreg[nt] = __builtin_amdgcn_mfma_f32_16x16x32_bf16(a, bf, z, 0, 0, 0);
        }
    }
    for (int item = tid; item < 576; item += 256) {
        int px = item / 9, pt = item - (item / 9) * 9;
        int lx = px & 15, ly = px >> 4;
        int hup = th * 4 + ly, wup = tw * 16 + lx;
        int lr = (ly >> 1) * 8 + (lx >> 1);
        int ij = ((hup & 1) << 1) | (wup & 1);
        float offy = sOff[lr * 72 + pt * 8 + ij];
        float offx = sOff[lr * 72 + pt * 8 + 4 + ij];
        float py  = offy + hup * 0.5f - 0.25f;
        float pxx = offx + wup * 0.5f - 0.25f;
        float y0f = floorf(py), x0f = floorf(pxx);
        float ty = py - y0f, tx = pxx - x0f;
        int y0 = (int)y0f, x0 = (int)x0f;
        int mk = 0;
        if ((unsigned)y0 < 64u && (unsigned)x0 < 64u)         mk |= 1;
        if ((unsigned)y0 < 64u && (unsigned)(x0+1) < 64u)     mk |= 2;
        if ((unsigned)(y0+1) < 64u && (unsigned)x0 < 64u)     mk |= 4;
        if ((unsigned)(y0+1) < 64u && (unsigned)(x0+1) < 64u) mk |= 8;
        int iy = y0 - ry0, ix = x0 - rx0;
        bool inreg = ((unsigned)iy <= (unsigned)(RROWS - 2)) &&
                     ((unsigned)ix <= (unsigned)(RCOLS - 2));
        int fl, zp;
        if (!mk)        { fl = 16; zp = 0; }
        else if (inreg) { fl = mk | 16; zp = iy * RCOLS + ix; }
        else            { fl = mk; zp = (y0 + 1) * 66 + (x0 + 1); }
        sGt[item] = (uint)f2h(ty) | ((uint)f2h(tx) << 16);
        sGz[item] = (zp << 5) | fl;
    }
    __syncthreads();

    // ---------------- P1: store S as fp16 (overwrites sOff) ----------------
#pragma unroll
    for (int nt = 0; nt < 5; ++nt) {
        int rp = nt * 16 + row;
        if (rp < RPX) {
#pragma unroll
            for (int r = 0; r < 4; ++r)
                sS[wv_ * 16 + kb8 * 4 + r][rp] = f2h(sreg[nt][r]);
        }
    }
    __syncthreads();

    // ---------------- P2: attention logits ---------------------------------
    for (int item = tid; item < 576; item += 256) {
        int px = item / 9;
        uint gt = sGt[item];
        float ty = h2f((ushort)gt), tx = h2f((ushort)(gt >> 16));
        int z = sGz[item];
        int fl = z & 31;
        float a;
        if (fl & 16) {
            int zi = z >> 5;
            float w00 = (1.f - ty) * (1.f - tx), w01 = (1.f - ty) * tx;
            float w10 = ty * (1.f - tx), w11 = ty * tx;
            a  = (fl & 1) ? w00 * h2f(sS[px][zi])             : 0.f;
            a += (fl & 2) ? w01 * h2f(sS[px][zi + 1])         : 0.f;
            a += (fl & 4) ? w10 * h2f(sS[px][zi + RCOLS])     : 0.f;
            a += (fl & 8) ? w11 * h2f(sS[px][zi + RCOLS + 1]) : 0.f;
        } else {
            int t = z >> 5;
            int y0 = t / 66 - 1, x0 = t - (t / 66) * 66 - 1;
            a = 0.f;
#pragma unroll
            for (int c = 0; c < 4; ++c) if ((fl >> c) & 1) {
                int dy = c >> 1, dx = c & 1;
                float wgt = (dy ? ty : 1.f - ty) * (dx ? tx : 1.f - tx);
                const ushort* kr = &kbf[((size_t)b * 4096 + (y0 + dy) * 64 + x0 + dx) * 128 +
                                        g * EMB];
                float dot = 0.f;
                for (int e = 0; e < EMB; ++e) dot += bf2f(sQ[px][e]) * bf2f(kr[e]);
                a += wgt * dot;
            }
            int old = atomicAdd(&sFB[0], 1);
            if (old < 128) sFB[1 + old] = item;
        }
        sAttn[item] = a;
    }
    __syncthreads();

    // ---------------- P3: softmax (tid<64)  |  zero W fp32 (tid>=64) -------
    if (tid < 64) {
        float aa[NPT];
        float mx = -1e30f;
#pragma unroll
        for (int p = 0; p < NPT; ++p) { aa[p] = sAttn[tid * 9 + p]; mx = fmaxf(mx, aa[p]); }
        float s = 0.f;
#pragma unroll
        for (int p = 0; p < NPT; ++p) { aa[p] = __expf(aa[p] - mx); s += aa[p]; }
        float inv = 1.f / s;
#pragma unroll
        for (int p = 0; p < NPT; ++p) sAttn[tid * 9 + p] = aa[p] * inv;
    } else {
        float4* p = (float4*)&sW[0][0];
        float4 z4 = make_float4(0.f, 0.f, 0.f, 0.f);
        for (int i = tid - 64; i < 1088; i += 192) p[i] = z4;
    }
    __syncthreads();

    // ---------------- P4: parallel W-build (256 thr = corner x px) ---------
    {
        int corner = tid >> 6, px = tid & 63;
        int dy = corner >> 1, dx = corner & 1;
#pragma unroll
        for (int pt = 0; pt < NPT; ++pt) {
            int item = px * 9 + pt;
            int z = sGz[item];
            int fl = z & 31;
            if ((fl & 16) && ((fl >> corner) & 1)) {
                uint gt = sGt[item];
                float ty = h2f((ushort)gt), tx = h2f((ushort)(gt >> 16));
                float w = (dy ? ty : 1.f - ty) * (dx ? tx : 1.f - tx) * sAttn[item];
                atomicAdd(&sW[px][(z >> 5) + dy * RCOLS + dx], w);
            }
        }
    }
    __syncthreads();

    // ---------------- P5: O-GEMM (f16 MFMA, K=64) + rp64/65 fix + store ----
    {
        half8v bfm[2][4];
#pragma unroll
        for (int kt = 0; kt < 2; ++kt)
#pragma unroll
            for (int nt = 0; nt < 4; ++nt)
                bfm[kt][nt] = *(const half8v*)&sXt[nt * 16 + row][kt * 32 + kb8 * 8];

        int px = wv_ * 16 + row;
        half8v af0, af1;
        {
            f32x4 wA = *(const f32x4*)&sW[px][kb8 * 8];
            f32x4 wB = *(const f32x4*)&sW[px][kb8 * 8 + 4];
            f32x4 wC = *(const f32x4*)&sW[px][32 + kb8 * 8];
            f32x4 wD = *(const f32x4*)&sW[px][32 + kb8 * 8 + 4];
#pragma unroll
            for (int j = 0; j < 4; ++j) {
                af0[j]     = (_Float16)wA[j];
                af0[j + 4] = (_Float16)wB[j];
                af1[j]     = (_Float16)wC[j];
                af1[j + 4] = (_Float16)wD[j];
            }
        }

        f32x4 acc[4];
#pragma unroll
        for (int nt = 0; nt < 4; ++nt) { f32x4 z = {0.f,0.f,0.f,0.f}; acc[nt] = z; }
#pragma unroll
        for (int nt = 0; nt < 4; ++nt) {
            acc[nt] = __builtin_amdgcn_mfma_f32_16x16x32_f16(af0, bfm[0][nt], acc[nt], 0, 0, 0);
            acc[nt] = __builtin_amdgcn_mfma_f32_16x16x32_f16(af1, bfm[1][nt], acc[nt], 0, 0, 0);
        }
        // correction for K columns 64,65 (W cols 64-65 x X cols 64-65)
        float wc[4][2];
#pragma unroll
        for (int r = 0; r < 4; ++r) {
            wc[r][0] = sW[wv_ * 16 + kb8 * 4 + r][64];
            wc[r][1] = sW[wv_ * 16 + kb8 * 4 + r][65];
        }
#pragma unroll
        for (int nt = 0; nt < 4; ++nt) {
            uint u = *(uint*)&sXt[nt * 16 + row][64];
            float x0 = h2f((ushort)u), x1 = h2f((ushort)(u >> 16));
#pragma unroll
            for (int r = 0; r < 4; ++r)
                acc[nt][r] += wc[r][0] * x0 + wc[r][1] * x1;
        }
        int hup = th * 4 + wv_;
#pragma unroll
        for (int nt = 0; nt < 4; ++nt) {
            int ch = nt * 16 + row;
            float* ob = out + ((size_t)b * 256 + g * CGRP + ch) * 16384 +
                        hup * 128 + tw * 16 + kb8 * 4;
#pragma unroll
            for (int r = 0; r < 4; ++r) ob[r] = acc[nt][r];
        }
    }
    __syncthreads();

    // ---------------- P6: rare out-of-region fallback -----------------------
    int nfb = min(sFB[0], 128);
    for (int i = 0; i < nfb; ++i) {
        if (tid < 64) {
            int item = sFB[1 + i];
            int px = item / 9;
            uint gt = sGt[item];
            float ty = h2f((ushort)gt), tx = h2f((ushort)(gt >> 16));
            int z = sGz[item];
            float a = sAttn[item];
            int fl = z & 15;
            int t = z >> 5;
            int y0 = t / 66 - 1, x0 = t - (t / 66) * 66 - 1;
            const float* xg = x + ((size_t)b * 256 + g * CGRP + tid) * 4096;
            float v = 0.f;
            if (fl & 1) v += (1.f-ty)*(1.f-tx)*a * xg[y0*64 + x0];
            if (fl & 2) v += (1.f-ty)*tx*a       * xg[y0*64 + x0 + 1];
            if (fl & 4) v += ty*(1.f-tx)*a       * xg[(y0+1)*64 + x0];
            if (fl & 8) v += ty*tx*a             * xg[(y0+1)*64 + x0 + 1];
            int hup = th * 4 + (px >> 4), wup = tw * 16 + (px & 15);
            float* op = out + ((size_t)b * 256 + g * CGRP + tid) * 16384 +
                        hup * 128 + wup;
            *op += v;
        }
    }
}

// ---------------------------------------------------------------------------
extern "C" void kernel_launch(void* const* d_in, const int* in_sizes, int n_in,
                              void* d_out, int out_size, void* d_ws, size_t ws_size,
                              hipStream_t stream)
{
    const float* y    = (const float*)d_in[0];
    const float* x    = (const float*)d_in[1];
    const float* Wq   = (const float*)d_in[2];
    const float* bq   = (const float*)d_in[3];
    const float* Wk   = (const float*)d_in[4];
    const float* bk   = (const float*)d_in[5];
    const float* Woff = (const float*)d_in[6];
    const float* boff = (const float*)d_in[7];
    float* out = (float*)d_out;

    // workspace layout (~19.9 MB total)
    ushort* qbf   = (ushort*)d_ws;                            // 2*16384*128
    ushort* kbf   = qbf + (size_t)B_N * 16384 * 128;          // 2*4096*128
    float*  offw  = (float*)(kbf + (size_t)B_N * 4096 * 128); // 2*4096*288

    // both convs in one pipelined launch (weights converted in-kernel)
    mfma_gemm<<<dim3(1024), dim3(256), 0, stream>>>(
        y, x, Wq, Wk, Woff, bq, bk, boff, qbf, kbf, offw);

    // fused deformable attention
    deform_kernel<<<dim3(2048), dim3(256), 0, stream>>>(qbf, kbf, offw, x, out);
}

// Round 14
// 64.728 us; speedup vs baseline: 1.2011x; 1.2011x over previous
//
#include <hip/hip_runtime.h>

// Problem constants
#define B_N   2
#define H_LR  64
#define W_LR  64
#define HUP   128
#define WUP   128
#define GRP   4
#define NPT   9
#define EMB   32
#define CGRP  64
#define KIN   256
#define GE    128
#define NOFF  288

typedef __attribute__((ext_vector_type(8))) short short8v;
typedef _Float16 half8v __attribute__((ext_vector_type(8)));
typedef __attribute__((ext_vector_type(4))) float f32x4;

__device__ __forceinline__ ushort f2bf(float f) {
    unsigned u = __float_as_uint(f);
    u += 0x7FFFu + ((u >> 16) & 1u);
    return (ushort)(u >> 16);
}
__device__ __forceinline__ float bf2f(ushort h) {
    return __uint_as_float(((unsigned)h) << 16);
}
__device__ __forceinline__ ushort f2h(float f) {
    _Float16 h = (_Float16)f;
    return __builtin_bit_cast(ushort, h);
}
__device__ __forceinline__ float h2f(ushort u) {
    _Float16 h = __builtin_bit_cast(_Float16, u);
    return (float)h;
}

// ---------------------------------------------------------------------------
// Merged bf16 MFMA GEMM for both 1x1 convs, register-prefetch pipelined.
// (unchanged — frozen since round 11)
// ---------------------------------------------------------------------------
__global__ __launch_bounds__(256, 4) void mfma_gemm(
    const float* __restrict__ y, const float* __restrict__ x,
    const float* __restrict__ Wq, const float* __restrict__ Wk,
    const float* __restrict__ Woff,
    const float* __restrict__ bq, const float* __restrict__ bk,
    const float* __restrict__ boff,
    ushort* __restrict__ qbf, ushort* __restrict__ kbf,
    float* __restrict__ offw)
{
    __shared__ __align__(16) ushort sY[64][68];
    __shared__ __align__(16) ushort sB[128][72];

    int bid = blockIdx.x;
    const float* SRC; const float* ba; const float* bb;
    ushort* OBF; float* OFP;
    int M, m0, n0, b;
    bool isQ = (bid < 512);
    if (isQ) {
        int mt = bid & 255; b = bid >> 8;
        SRC = y; ba = bq; bb = nullptr; OBF = qbf; OFP = nullptr;
        M = 16384; m0 = mt * 64; n0 = 0;
    } else {
        int r = bid - 512;
        int mt = r & 63, nt2 = (r >> 6) & 3; b = r >> 8;
        SRC = x; ba = bk; bb = boff; OBF = kbf; OFP = offw;
        M = 4096; m0 = mt * 64; n0 = nt2 * 128;
    }

    int tid = threadIdx.x;
    int lane = tid & 63;
    int wv = tid >> 6, wm = wv >> 1, wn = wv & 1;
    int il = lane & 15, g4 = lane >> 4;
    int st_m4 = tid & 15, st_c = tid >> 4;
    int st_c8 = tid & 7,  st_n = tid >> 3;

    const float* wrowp[4];
#pragma unroll
    for (int i = 0; i < 4; ++i) {
        int n = n0 + st_n + i * 32;
        if (isQ)            wrowp[i] = Wq  + (size_t)n * KIN;
        else if (n < GE)    wrowp[i] = Wk  + (size_t)n * KIN;
        else if (n < GE + NOFF) wrowp[i] = Woff + (size_t)(n - GE) * KIN;
        else                wrowp[i] = nullptr;
    }

    f32x4 acc[2][4];
#pragma unroll
    for (int i = 0; i < 2; ++i)
#pragma unroll
        for (int j = 0; j < 4; ++j) { f32x4 z = {0.f,0.f,0.f,0.f}; acc[i][j] = z; }

    const float* src_b = SRC + (size_t)b * KIN * M;

    float4 ra[4]; short8v rb[4];
#pragma unroll
    for (int i = 0; i < 4; ++i)
        ra[i] = *(const float4*)&src_b[(size_t)(st_c + i * 16) * M + m0 + st_m4 * 4];
#pragma unroll
    for (int i = 0; i < 4; ++i) {
        short8v t = {0,0,0,0,0,0,0,0};
        if (wrowp[i]) {
            float4 a = *(const float4*)&wrowp[i][st_c8 * 8];
            float4 c = *(const float4*)&wrowp[i][st_c8 * 8 + 4];
            t[0]=(short)f2bf(a.x); t[1]=(short)f2bf(a.y); t[2]=(short)f2bf(a.z); t[3]=(short)f2bf(a.w);
            t[4]=(short)f2bf(c.x); t[5]=(short)f2bf(c.y); t[6]=(short)f2bf(c.z); t[7]=(short)f2bf(c.w);
        }
        rb[i] = t;
    }

    for (int ks = 0; ks < 4; ++ks) {
#pragma unroll
        for (int i = 0; i < 4; ++i) {
            ushort4 h;
            h.x = f2bf(ra[i].x); h.y = f2bf(ra[i].y);
            h.z = f2bf(ra[i].z); h.w = f2bf(ra[i].w);
            *(ushort4*)&sY[st_c + i * 16][st_m4 * 4] = h;
            *(short8v*)&sB[st_n + i * 32][st_c8 * 8] = rb[i];
        }
        __syncthreads();
        if (ks < 3) {
            int k0 = (ks + 1) * 64;
#pragma unroll
            for (int i = 0; i < 4; ++i)
                ra[i] = *(const float4*)&src_b[(size_t)(k0 + st_c + i * 16) * M + m0 + st_m4 * 4];
#pragma unroll
            for (int i = 0; i < 4; ++i) {
                short8v t = {0,0,0,0,0,0,0,0};
                if (wrowp[i]) {
                    float4 a = *(const float4*)&wrowp[i][k0 + st_c8 * 8];
                    float4 c = *(const float4*)&wrowp[i][k0 + st_c8 * 8 + 4];
                    t[0]=(short)f2bf(a.x); t[1]=(short)f2bf(a.y); t[2]=(short)f2bf(a.z); t[3]=(short)f2bf(a.w);
                    t[4]=(short)f2bf(c.x); t[5]=(short)f2bf(c.y); t[6]=(short)f2bf(c.z); t[7]=(short)f2bf(c.w);
                }
                rb[i] = t;
            }
        }
#pragma unroll
        for (int kc = 0; kc < 2; ++kc) {
            int kb = kc * 32 + g4 * 8;
            short8v af[2], bfr[4];
#pragma unroll
            for (int mf = 0; mf < 2; ++mf) {
                int m = wm * 32 + mf * 16 + il;
                short8v t;
#pragma unroll
                for (int j = 0; j < 8; ++j) t[j] = (short)sY[kb + j][m];
                af[mf] = t;
            }
#pragma unroll
            for (int nf = 0; nf < 4; ++nf)
                bfr[nf] = *(const short8v*)&sB[wn * 64 + nf * 16 + il][kb];
#pragma unroll
            for (int mf = 0; mf < 2; ++mf)
#pragma unroll
                for (int nf = 0; nf < 4; ++nf)
                    acc[mf][nf] = __builtin_amdgcn_mfma_f32_16x16x32_bf16(
                        af[mf], bfr[nf], acc[mf][nf], 0, 0, 0);
        }
        __syncthreads();
    }

#pragma unroll
    for (int mf = 0; mf < 2; ++mf) {
#pragma unroll
        for (int r = 0; r < 4; ++r) {
            int m = m0 + wm * 32 + mf * 16 + g4 * 4 + r;
            size_t row = (size_t)b * M + m;
#pragma unroll
            for (int nf = 0; nf < 4; ++nf) {
                int n = n0 + wn * 64 + nf * 16 + il;
                float v = acc[mf][nf][r];
                if (n < GE) {
                    OBF[row * 128 + n] = f2bf(v + ba[n]);
                } else {
                    int no = n - GE;
                    if (no < NOFF) OFP[row * 288 + no] = v + bb[no];
                }
            }
        }
    }
}

// ---------------------------------------------------------------------------
// Fused deformable attention via per-block dense MFMA GEMMs.
// Round-12 proven structure (serial fp16 RMW W-build) with sQ deleted:
// q MFMA fragments and fallback-q come directly from global (L2-hot).
// LDS 30.4 KB -> 5 blocks/CU.
// ---------------------------------------------------------------------------
#define RROWS 6
#define RCOLS 11
#define RPX   66

__global__ __launch_bounds__(256, 5) void deform_kernel(
    const ushort* __restrict__ qbf,  // [B, 16384, 128] bf16 pixel-major
    const ushort* __restrict__ kbf,  // [B, 4096, 128] bf16 pixel-major
    const float* __restrict__ offw,  // [B, 4096, 288] fp32 pixel-major
    const float* __restrict__ x,     // [B, 256, 64, 64] channel-major (input)
    float* __restrict__ out)         // [B, 256, 128, 128]
{
    __shared__ __align__(16) char smem[31152];
    ushort (*sXt)[72] = (ushort(*)[72])(smem);            // [0,9216)      x region fp16
    ushort (*sK)[40]  = (ushort(*)[40])(smem + 9216);     // [9216,14496)  k region bf16
    ushort (*sSW)[72] = (ushort(*)[72])(smem + 14496);    // [14496,23712) off fp32 / S,W fp16
    uint*  sGt        = (uint*)(smem + 23712);            // [23712,26016)
    int*   sGz        = (int*)(smem + 26016);             // [26016,28320)
    float* sAttn      = (float*)(smem + 28320);           // [28320,30624)
    int*   sFB        = (int*)(smem + 30624);             // [30624,31140)
    float* sOff       = (float*)(smem + 14496);           // [16][72] fp32 alias (pre-S)

    int bx = blockIdx.x;
    int tw = bx & 7, th = (bx >> 3) & 31, g = (bx >> 8) & 3, b = bx >> 10;
    int tid = threadIdx.x;
    int wv_ = tid >> 6, lane = tid & 63;
    int row = lane & 15, kb8 = lane >> 4;

    const int ry0 = th * 2 - 2, rx0 = tw * 8 - 1;

    // ---------------- P0a: all staging (coalesced) -------------------------
    if (tid == 0) sFB[0] = 0;
    // x region -> fp16, pair-packed u32 stores
    for (int s = tid; s < 384; s += 256) {
        int gy = s % 6, ch = s / 6;
        int gyg = min(max(ry0 + gy, 0), 63);
        const float* xr = x + ((size_t)b * 256 + g * CGRP + ch) * 4096 + gyg * 64;
        float v[11];
        if (tw >= 1 && tw <= 6) {
            int a0 = rx0 - 3;                    // 16B-aligned, in-bounds
            float tmp[16];
#pragma unroll
            for (int t4 = 0; t4 < 4; ++t4) {
                float4 f = *(const float4*)&xr[a0 + t4 * 4];
                tmp[t4*4+0] = f.x; tmp[t4*4+1] = f.y; tmp[t4*4+2] = f.z; tmp[t4*4+3] = f.w;
            }
#pragma unroll
            for (int qx = 0; qx < RCOLS; ++qx) v[qx] = tmp[qx + 3];
        } else {
#pragma unroll
            for (int qx = 0; qx < RCOLS; ++qx) {
                int gxg = min(max(rx0 + qx, 0), 63);
                v[qx] = xr[gxg];
            }
        }
        ushort* dst = &sXt[ch][0];
        int c0 = gy * RCOLS;
        if (c0 & 1) {
            dst[c0] = f2h(v[0]);
#pragma unroll
            for (int j = 0; j < 5; ++j)
                *(uint*)&dst[c0 + 1 + 2*j] =
                    (uint)f2h(v[1 + 2*j]) | ((uint)f2h(v[2 + 2*j]) << 16);
        } else {
#pragma unroll
            for (int j = 0; j < 5; ++j)
                *(uint*)&dst[c0 + 2*j] =
                    (uint)f2h(v[2*j]) | ((uint)f2h(v[1 + 2*j]) << 16);
            dst[c0 + 10] = f2h(v[10]);
        }
    }
    // k region bf16
    for (int i = tid; i < 264; i += 256) {
        int rp = i >> 2, c4 = i & 3;
        int qy = rp / RCOLS, qx = rp - qy * RCOLS;
        int gy = min(max(ry0 + qy, 0), 63), gx = min(max(rx0 + qx, 0), 63);
        *(short8v*)&sK[rp][c4 * 8] =
            *(const short8v*)&kbf[((size_t)b * 4096 + gy * 64 + gx) * 128 +
                                  g * EMB + c4 * 8];
    }
    // offsets (coalesced float4) -> sOff
    for (int i = tid; i < 288; i += 256) {
        int lr = i / 18, f4 = i - (i / 18) * 18;
        int yy = th * 2 + (lr >> 3), xx = tw * 8 + (lr & 7);
        *(float4*)&sOff[lr * 72 + f4 * 4] =
            *(const float4*)&offw[((size_t)b * 4096 + yy * 64 + xx) * 288 +
                                  g * 72 + f4 * 4];
    }
    __syncthreads();

    // ---------------- P0b: S-GEMM (to regs, q from global) + geometry ------
    f32x4 sreg[5];
    {
        int px = wv_ * 16 + row;
        int hup = th * 4 + (px >> 4), wup = tw * 16 + (px & 15);
        short8v a = *(const short8v*)&qbf[((size_t)b * 16384 + hup * 128 + wup) * 128 +
                                          g * EMB + kb8 * 8];
#pragma unroll
        for (int nt = 0; nt < 5; ++nt) {
            int rr = nt * 16 + row; if (rr > 65) rr = 65;   // tail clamp
            short8v bf = *(const short8v*)&sK[rr][kb8 * 8];
            f32x4 z = {0.f, 0.f, 0.f, 0.f};
            sreg[nt] = __builtin_amdgcn_mfma_f32_16x16x32_bf16(a, bf, z, 0, 0, 0);
        }
    }
    for (int item = tid; item < 576; item += 256) {
        int px = item / 9, pt = item - (item / 9) * 9;
        int lx = px & 15, ly = px >> 4;
        int hup = th * 4 + ly, wup = tw * 16 + lx;
        int lr = (ly >> 1) * 8 + (lx >> 1);
        int ij = ((hup & 1) << 1) | (wup & 1);
        float offy = sOff[lr * 72 + pt * 8 + ij];
        float offx = sOff[lr * 72 + pt * 8 + 4 + ij];
        float py  = offy + hup * 0.5f - 0.25f;
        float pxx = offx + wup * 0.5f - 0.25f;
        float y0f = floorf(py), x0f = floorf(pxx);
        float ty = py - y0f, tx = pxx - x0f;
        int y0 = (int)y0f, x0 = (int)x0f;
        int mk = 0;
        if ((unsigned)y0 < 64u && (unsigned)x0 < 64u)         mk |= 1;
        if ((unsigned)y0 < 64u && (unsigned)(x0+1) < 64u)     mk |= 2;
        if ((unsigned)(y0+1) < 64u && (unsigned)x0 < 64u)     mk |= 4;
        if ((unsigned)(y0+1) < 64u && (unsigned)(x0+1) < 64u) mk |= 8;
        int iy = y0 - ry0, ix = x0 - rx0;
        bool inreg = ((unsigned)iy <= (unsigned)(RROWS - 2)) &&
                     ((unsigned)ix <= (unsigned)(RCOLS - 2));
        int fl, zp;
        if (!mk)        { fl = 16; zp = 0; }
        else if (inreg) { fl = mk | 16; zp = iy * RCOLS + ix; }
        else            { fl = mk; zp = (y0 + 1) * 66 + (x0 + 1); }
        sGt[item] = (uint)f2h(ty) | ((uint)f2h(tx) << 16);
        sGz[item] = (zp << 5) | fl;
    }
    __syncthreads();

    // ---------------- P1: store S as fp16 (overwrites sOff) ----------------
#pragma unroll
    for (int nt = 0; nt < 5; ++nt) {
        int rp = nt * 16 + row;
        if (rp < RPX) {
#pragma unroll
            for (int r = 0; r < 4; ++r)
                sSW[wv_ * 16 + kb8 * 4 + r][rp] = f2h(sreg[nt][r]);
        }
    }
    __syncthreads();

    // ---------------- P2: attention logits ---------------------------------
    for (int item = tid; item < 576; item += 256) {
        int px = item / 9;
        uint gt = sGt[item];
        float ty = h2f((ushort)gt), tx = h2f((ushort)(gt >> 16));
        int z = sGz[item];
        int fl = z & 31;
        float a;
        if (fl & 16) {
            int zi = z >> 5;
            float w00 = (1.f - ty) * (1.f - tx), w01 = (1.f - ty) * tx;
            float w10 = ty * (1.f - tx), w11 = ty * tx;
            a  = (fl & 1) ? w00 * h2f(sSW[px][zi])             : 0.f;
            a += (fl & 2) ? w01 * h2f(sSW[px][zi + 1])         : 0.f;
            a += (fl & 4) ? w10 * h2f(sSW[px][zi + RCOLS])     : 0.f;
            a += (fl & 8) ? w11 * h2f(sSW[px][zi + RCOLS + 1]) : 0.f;
        } else {
            int t = z >> 5;
            int y0 = t / 66 - 1, x0 = t - (t / 66) * 66 - 1;
            int hq = th * 4 + (px >> 4), wq = tw * 16 + (px & 15);
            const ushort* qr = &qbf[((size_t)b * 16384 + hq * 128 + wq) * 128 + g * EMB];
            a = 0.f;
#pragma unroll
            for (int c = 0; c < 4; ++c) if ((fl >> c) & 1) {
                int dy = c >> 1, dx = c & 1;
                float wgt = (dy ? ty : 1.f - ty) * (dx ? tx : 1.f - tx);
                const ushort* kr = &kbf[((size_t)b * 4096 + (y0 + dy) * 64 + x0 + dx) * 128 +
                                        g * EMB];
                float dot = 0.f;
                for (int e = 0; e < EMB; ++e) dot += bf2f(qr[e]) * bf2f(kr[e]);
                a += wgt * dot;
            }
            int old = atomicAdd(&sFB[0], 1);
            if (old < 128) sFB[1 + old] = item;
        }
        sAttn[item] = a;
    }
    __syncthreads();

    // ---------------- P3: softmax (tid<64)  |  zero W (tid>=64) ------------
    if (tid < 64) {
        float aa[NPT];
        float mx = -1e30f;
#pragma unroll
        for (int p = 0; p < NPT; ++p) { aa[p] = sAttn[tid * 9 + p]; mx = fmaxf(mx, aa[p]); }
        float s = 0.f;
#pragma unroll
        for (int p = 0; p < NPT; ++p) { aa[p] = __expf(aa[p] - mx); s += aa[p]; }
        float inv = 1.f / s;
#pragma unroll
        for (int p = 0; p < NPT; ++p) sAttn[tid * 9 + p] = aa[p] * inv;
    } else {
        float4* p = (float4*)&sSW[0][0];
        float4 z4 = make_float4(0.f, 0.f, 0.f, 0.f);
        for (int i = tid - 64; i < 576; i += 192) p[i] = z4;
    }
    __syncthreads();

    // ---------------- P4: W-build (tid<64, serial fp16 RMW) ----------------
    if (tid < 64) {
        int px = tid;
#pragma unroll
        for (int pt = 0; pt < NPT; ++pt) {
            int item = px * 9 + pt;
            int z = sGz[item];
            int fl = z & 31;
            if (!(fl & 16)) continue;
            uint gt = sGt[item];
            float ty = h2f((ushort)gt), tx = h2f((ushort)(gt >> 16));
            float a = sAttn[item];
            int zi = z >> 5;
            ushort* c = &sSW[px][zi];
            if (fl & 1) c[0]         = f2h(h2f(c[0])         + (1.f-ty)*(1.f-tx)*a);
            if (fl & 2) c[1]         = f2h(h2f(c[1])         + (1.f-ty)*tx*a);
            if (fl & 4) c[RCOLS]     = f2h(h2f(c[RCOLS])     + ty*(1.f-tx)*a);
            if (fl & 8) c[RCOLS + 1] = f2h(h2f(c[RCOLS + 1]) + ty*tx*a);
        }
    }
    __syncthreads();

    // ---------------- P5: O-GEMM (f16 MFMA, K=64) + rp64/65 fix + store ----
    {
        half8v bfm[2][4];
#pragma unroll
        for (int kt = 0; kt < 2; ++kt)
#pragma unroll
            for (int nt = 0; nt < 4; ++nt)
                bfm[kt][nt] = *(const half8v*)&sXt[nt * 16 + row][kt * 32 + kb8 * 8];

        int px = wv_ * 16 + row;
        half8v af0 = *(const half8v*)&sSW[px][kb8 * 8];
        half8v af1 = *(const half8v*)&sSW[px][32 + kb8 * 8];

        f32x4 acc[4];
#pragma unroll
        for (int nt = 0; nt < 4; ++nt) { f32x4 z = {0.f,0.f,0.f,0.f}; acc[nt] = z; }
#pragma unroll
        for (int nt = 0; nt < 4; ++nt) {
            acc[nt] = __builtin_amdgcn_mfma_f32_16x16x32_f16(af0, bfm[0][nt], acc[nt], 0, 0, 0);
            acc[nt] = __builtin_amdgcn_mfma_f32_16x16x32_f16(af1, bfm[1][nt], acc[nt], 0, 0, 0);
        }
        // correction for K columns 64,65 (W cols 64-65 x X cols 64-65)
        float wc[4][2];
#pragma unroll
        for (int r = 0; r < 4; ++r) {
            uint u = *(uint*)&sSW[wv_ * 16 + kb8 * 4 + r][64];
            wc[r][0] = h2f((ushort)u); wc[r][1] = h2f((ushort)(u >> 16));
        }
#pragma unroll
        for (int nt = 0; nt < 4; ++nt) {
            uint u = *(uint*)&sXt[nt * 16 + row][64];
            float x0 = h2f((ushort)u), x1 = h2f((ushort)(u >> 16));
#pragma unroll
            for (int r = 0; r < 4; ++r)
                acc[nt][r] += wc[r][0] * x0 + wc[r][1] * x1;
        }
        int hup = th * 4 + wv_;
#pragma unroll
        for (int nt = 0; nt < 4; ++nt) {
            int ch = nt * 16 + row;
            float* ob = out + ((size_t)b * 256 + g * CGRP + ch) * 16384 +
                        hup * 128 + tw * 16 + kb8 * 4;
#pragma unroll
            for (int r = 0; r < 4; ++r) ob[r] = acc[nt][r];
        }
    }
    __syncthreads();

    // ---------------- P6: rare out-of-region fallback -----------------------
    int nfb = min(sFB[0], 128);
    for (int i = 0; i < nfb; ++i) {
        if (tid < 64) {
            int item = sFB[1 + i];
            int px = item / 9;
            uint gt = sGt[item];
            float ty = h2f((ushort)gt), tx = h2f((ushort)(gt >> 16));
            int z = sGz[item];
            float a = sAttn[item];
            int fl = z & 15;
            int t = z >> 5;
            int y0 = t / 66 - 1, x0 = t - (t / 66) * 66 - 1;
            const float* xg = x + ((size_t)b * 256 + g * CGRP + tid) * 4096;
            float v = 0.f;
            if (fl & 1) v += (1.f-ty)*(1.f-tx)*a * xg[y0*64 + x0];
            if (fl & 2) v += (1.f-ty)*tx*a       * xg[y0*64 + x0 + 1];
            if (fl & 4) v += ty*(1.f-tx)*a       * xg[(y0+1)*64 + x0];
            if (fl & 8) v += ty*tx*a             * xg[(y0+1)*64 + x0 + 1];
            int hup = th * 4 + (px >> 4), wup = tw * 16 + (px & 15);
            float* op = out + ((size_t)b * 256 + g * CGRP + tid) * 16384 +
                        hup * 128 + wup;
            *op += v;
        }
    }
}

// ---------------------------------------------------------------------------
extern "C" void kernel_launch(void* const* d_in, const int* in_sizes, int n_in,
                              void* d_out, int out_size, void* d_ws, size_t ws_size,
                              hipStream_t stream)
{
    const float* y    = (const float*)d_in[0];
    const float* x    = (const float*)d_in[1];
    const float* Wq   = (const float*)d_in[2];
    const float* bq   = (const float*)d_in[3];
    const float* Wk   = (const float*)d_in[4];
    const float* bk   = (const float*)d_in[5];
    const float* Woff = (const float*)d_in[6];
    const float* boff = (const float*)d_in[7];
    float* out = (float*)d_out;

    // workspace layout (~19.9 MB total)
    ushort* qbf   = (ushort*)d_ws;                            // 2*16384*128
    ushort* kbf   = qbf + (size_t)B_N * 16384 * 128;          // 2*4096*128
    float*  offw  = (float*)(kbf + (size_t)B_N * 4096 * 128); // 2*4096*288

    // both convs in one pipelined launch (weights converted in-kernel)
    mfma_gemm<<<dim3(1024), dim3(256), 0, stream>>>(
        y, x, Wq, Wk, Woff, bq, bk, boff, qbf, kbf, offw);

    // fused deformable attention
    deform_kernel<<<dim3(2048), dim3(256), 0, stream>>>(qbf, kbf, offw, x, out);
}

// Round 15
// 63.031 us; speedup vs baseline: 1.2334x; 1.0269x over previous
//
#include <hip/hip_runtime.h>

// Problem constants
#define B_N   2
#define H_LR  64
#define W_LR  64
#define HUP   128
#define WUP   128
#define GRP   4
#define NPT   9
#define EMB   32
#define CGRP  64
#define KIN   256
#define GE    128
#define NOFF  288

typedef __attribute__((ext_vector_type(8))) short short8v;
typedef _Float16 half8v __attribute__((ext_vector_type(8)));
typedef __attribute__((ext_vector_type(4))) float f32x4;

__device__ __forceinline__ ushort f2bf(float f) {
    unsigned u = __float_as_uint(f);
    u += 0x7FFFu + ((u >> 16) & 1u);
    return (ushort)(u >> 16);
}
__device__ __forceinline__ float bf2f(ushort h) {
    return __uint_as_float(((unsigned)h) << 16);
}
__device__ __forceinline__ ushort f2h(float f) {
    _Float16 h = (_Float16)f;
    return __builtin_bit_cast(ushort, h);
}
__device__ __forceinline__ float h2f(ushort u) {
    _Float16 h = __builtin_bit_cast(_Float16, u);
    return (float)h;
}

// ---------------------------------------------------------------------------
// Merged bf16 MFMA GEMM for both 1x1 convs, register-prefetch pipelined.
// Weights converted fp32 -> bf16 at prefetch time (no separate convert pass).
// blocks [0,512):   q  = Wq@y+bq    M=16384, BM=64, BN=128 (1 ntile)
// blocks [512,1024): koff = [Wk;Woff]@x+b  M=4096, BM=64, 4 ntiles of 128
// ---------------------------------------------------------------------------
__global__ __launch_bounds__(256, 4) void mfma_gemm(
    const float* __restrict__ y, const float* __restrict__ x,
    const float* __restrict__ Wq, const float* __restrict__ Wk,
    const float* __restrict__ Woff,
    const float* __restrict__ bq, const float* __restrict__ bk,
    const float* __restrict__ boff,
    ushort* __restrict__ qbf, ushort* __restrict__ kbf,
    float* __restrict__ offw)
{
    __shared__ __align__(16) ushort sY[64][68];
    __shared__ __align__(16) ushort sB[128][72];

    int bid = blockIdx.x;
    const float* SRC; const float* ba; const float* bb;
    ushort* OBF; float* OFP;
    int M, m0, n0, b;
    bool isQ = (bid < 512);
    if (isQ) {
        int mt = bid & 255; b = bid >> 8;
        SRC = y; ba = bq; bb = nullptr; OBF = qbf; OFP = nullptr;
        M = 16384; m0 = mt * 64; n0 = 0;
    } else {
        int r = bid - 512;
        int mt = r & 63, nt2 = (r >> 6) & 3; b = r >> 8;
        SRC = x; ba = bk; bb = boff; OBF = kbf; OFP = offw;
        M = 4096; m0 = mt * 64; n0 = nt2 * 128;
    }

    int tid = threadIdx.x;
    int lane = tid & 63;
    int wv = tid >> 6, wm = wv >> 1, wn = wv & 1;
    int il = lane & 15, g4 = lane >> 4;
    int st_m4 = tid & 15, st_c = tid >> 4;
    int st_c8 = tid & 7,  st_n = tid >> 3;

    const float* wrowp[4];
#pragma unroll
    for (int i = 0; i < 4; ++i) {
        int n = n0 + st_n + i * 32;
        if (isQ)            wrowp[i] = Wq  + (size_t)n * KIN;
        else if (n < GE)    wrowp[i] = Wk  + (size_t)n * KIN;
        else if (n < GE + NOFF) wrowp[i] = Woff + (size_t)(n - GE) * KIN;
        else                wrowp[i] = nullptr;
    }

    f32x4 acc[2][4];
#pragma unroll
    for (int i = 0; i < 2; ++i)
#pragma unroll
        for (int j = 0; j < 4; ++j) { f32x4 z = {0.f,0.f,0.f,0.f}; acc[i][j] = z; }

    const float* src_b = SRC + (size_t)b * KIN * M;

    float4 ra[4]; short8v rb[4];
#pragma unroll
    for (int i = 0; i < 4; ++i)
        ra[i] = *(const float4*)&src_b[(size_t)(st_c + i * 16) * M + m0 + st_m4 * 4];
#pragma unroll
    for (int i = 0; i < 4; ++i) {
        short8v t = {0,0,0,0,0,0,0,0};
        if (wrowp[i]) {
            float4 a = *(const float4*)&wrowp[i][st_c8 * 8];
            float4 c = *(const float4*)&wrowp[i][st_c8 * 8 + 4];
            t[0]=(short)f2bf(a.x); t[1]=(short)f2bf(a.y); t[2]=(short)f2bf(a.z); t[3]=(short)f2bf(a.w);
            t[4]=(short)f2bf(c.x); t[5]=(short)f2bf(c.y); t[6]=(short)f2bf(c.z); t[7]=(short)f2bf(c.w);
        }
        rb[i] = t;
    }

    for (int ks = 0; ks < 4; ++ks) {
#pragma unroll
        for (int i = 0; i < 4; ++i) {
            ushort4 h;
            h.x = f2bf(ra[i].x); h.y = f2bf(ra[i].y);
            h.z = f2bf(ra[i].z); h.w = f2bf(ra[i].w);
            *(ushort4*)&sY[st_c + i * 16][st_m4 * 4] = h;
            *(short8v*)&sB[st_n + i * 32][st_c8 * 8] = rb[i];
        }
        __syncthreads();
        if (ks < 3) {
            int k0 = (ks + 1) * 64;
#pragma unroll
            for (int i = 0; i < 4; ++i)
                ra[i] = *(const float4*)&src_b[(size_t)(k0 + st_c + i * 16) * M + m0 + st_m4 * 4];
#pragma unroll
            for (int i = 0; i < 4; ++i) {
                short8v t = {0,0,0,0,0,0,0,0};
                if (wrowp[i]) {
                    float4 a = *(const float4*)&wrowp[i][k0 + st_c8 * 8];
                    float4 c = *(const float4*)&wrowp[i][k0 + st_c8 * 8 + 4];
                    t[0]=(short)f2bf(a.x); t[1]=(short)f2bf(a.y); t[2]=(short)f2bf(a.z); t[3]=(short)f2bf(a.w);
                    t[4]=(short)f2bf(c.x); t[5]=(short)f2bf(c.y); t[6]=(short)f2bf(c.z); t[7]=(short)f2bf(c.w);
                }
                rb[i] = t;
            }
        }
#pragma unroll
        for (int kc = 0; kc < 2; ++kc) {
            int kb = kc * 32 + g4 * 8;
            short8v af[2], bfr[4];
#pragma unroll
            for (int mf = 0; mf < 2; ++mf) {
                int m = wm * 32 + mf * 16 + il;
                short8v t;
#pragma unroll
                for (int j = 0; j < 8; ++j) t[j] = (short)sY[kb + j][m];
                af[mf] = t;
            }
#pragma unroll
            for (int nf = 0; nf < 4; ++nf)
                bfr[nf] = *(const short8v*)&sB[wn * 64 + nf * 16 + il][kb];
#pragma unroll
            for (int mf = 0; mf < 2; ++mf)
#pragma unroll
                for (int nf = 0; nf < 4; ++nf)
                    acc[mf][nf] = __builtin_amdgcn_mfma_f32_16x16x32_bf16(
                        af[mf], bfr[nf], acc[mf][nf], 0, 0, 0);
        }
        __syncthreads();
    }

#pragma unroll
    for (int mf = 0; mf < 2; ++mf) {
#pragma unroll
        for (int r = 0; r < 4; ++r) {
            int m = m0 + wm * 32 + mf * 16 + g4 * 4 + r;
            size_t row = (size_t)b * M + m;
#pragma unroll
            for (int nf = 0; nf < 4; ++nf) {
                int n = n0 + wn * 64 + nf * 16 + il;
                float v = acc[mf][nf][r];
                if (n < GE) {
                    OBF[row * 128 + n] = f2bf(v + ba[n]);
                } else {
                    int no = n - GE;
                    if (no < NOFF) OFP[row * 288 + no] = v + bb[no];
                }
            }
        }
    }
}

// ---------------------------------------------------------------------------
// Fused deformable attention via per-block dense MFMA GEMMs.
// Best-measured round-11 structure (63.99 us total, deform 41.4 us), plus an
// XCD-aware block remap: grid 2048 = 8 x 256; wg = (bx&7)*256 + (bx>>3) puts
// each XCD on exactly one (b,g) pair, whose ~3.4 MB working set fits its L2.
// ---------------------------------------------------------------------------
#define RROWS 6
#define RCOLS 11
#define RPX   66

__global__ __launch_bounds__(256, 4) void deform_kernel(
    const ushort* __restrict__ qbf,  // [B, 16384, 128] bf16 pixel-major
    const ushort* __restrict__ kbf,  // [B, 4096, 128] bf16 pixel-major
    const float* __restrict__ offw,  // [B, 4096, 288] fp32 pixel-major
    const float* __restrict__ x,     // [B, 256, 64, 64] channel-major (input)
    float* __restrict__ out)         // [B, 256, 128, 128]
{
    __shared__ __align__(16) ushort sXt[64][72];  // x region fp16 [ch][rp 0..65]
    __shared__ __align__(16) ushort sK[66][40];   // k region bf16
    __shared__ __align__(16) ushort sQ[64][40];   // q bf16
    __shared__ __align__(16) ushort sSW[64][72];  // P0: sOff fp32; P1+: S then W fp16
    __shared__ uint   sGt[576];                   // packed {ty,tx} fp16
    __shared__ int    sGz[576];                   // packed zi + flags
    __shared__ float  sAttn[576];                 // logits -> normalized attn
    __shared__ int    sFB[129];                   // fallback list

    int bxl = blockIdx.x;
    // XCD-aware remap (bijective, 2048 % 8 == 0): XCD k <- one (b,g) pair
    int bx = (bxl & 7) * 256 + (bxl >> 3);
    int tw = bx & 7, th = (bx >> 3) & 31, g = (bx >> 8) & 3, b = bx >> 10;
    int tid = threadIdx.x;
    int wv_ = tid >> 6, lane = tid & 63;
    int row = lane & 15, kb8 = lane >> 4;

    const int ry0 = th * 2 - 2, rx0 = tw * 8 - 1;
    float* sOff = (float*)&sSW[0][0];             // [16][72] fp32 alias

    // ---------------- P0a: all staging (coalesced) -------------------------
    if (tid == 0) sFB[0] = 0;
    // x region -> fp16, pair-packed u32 stores
    for (int s = tid; s < 384; s += 256) {
        int gy = s % 6, ch = s / 6;
        int gyg = min(max(ry0 + gy, 0), 63);
        const float* xr = x + ((size_t)b * 256 + g * CGRP + ch) * 4096 + gyg * 64;
        float v[11];
        if (tw >= 1 && tw <= 6) {
            int a0 = rx0 - 3;                    // 16B-aligned, in-bounds
            float tmp[16];
#pragma unroll
            for (int t4 = 0; t4 < 4; ++t4) {
                float4 f = *(const float4*)&xr[a0 + t4 * 4];
                tmp[t4*4+0] = f.x; tmp[t4*4+1] = f.y; tmp[t4*4+2] = f.z; tmp[t4*4+3] = f.w;
            }
#pragma unroll
            for (int qx = 0; qx < RCOLS; ++qx) v[qx] = tmp[qx + 3];
        } else {
#pragma unroll
            for (int qx = 0; qx < RCOLS; ++qx) {
                int gxg = min(max(rx0 + qx, 0), 63);
                v[qx] = xr[gxg];
            }
        }
        ushort* dst = &sXt[ch][0];
        int c0 = gy * RCOLS;
        if (c0 & 1) {
            dst[c0] = f2h(v[0]);
#pragma unroll
            for (int j = 0; j < 5; ++j)
                *(uint*)&dst[c0 + 1 + 2*j] =
                    (uint)f2h(v[1 + 2*j]) | ((uint)f2h(v[2 + 2*j]) << 16);
        } else {
#pragma unroll
            for (int j = 0; j < 5; ++j)
                *(uint*)&dst[c0 + 2*j] =
                    (uint)f2h(v[2*j]) | ((uint)f2h(v[1 + 2*j]) << 16);
            dst[c0 + 10] = f2h(v[10]);
        }
    }
    // k region bf16
    for (int i = tid; i < 264; i += 256) {
        int rp = i >> 2, c4 = i & 3;
        int qy = rp / RCOLS, qx = rp - qy * RCOLS;
        int gy = min(max(ry0 + qy, 0), 63), gx = min(max(rx0 + qx, 0), 63);
        *(short8v*)&sK[rp][c4 * 8] =
            *(const short8v*)&kbf[((size_t)b * 4096 + gy * 64 + gx) * 128 +
                                  g * EMB + c4 * 8];
    }
    // q bf16
    {
        int px = tid >> 2, c4 = tid & 3;
        int hup = th * 4 + (px >> 4), wup = tw * 16 + (px & 15);
        *(short8v*)&sQ[px][c4 * 8] =
            *(const short8v*)&qbf[((size_t)b * 16384 + hup * 128 + wup) * 128 +
                                  g * EMB + c4 * 8];
    }
    // offsets (coalesced float4) -> sOff
    for (int i = tid; i < 288; i += 256) {
        int lr = i / 18, f4 = i - (i / 18) * 18;
        int yy = th * 2 + (lr >> 3), xx = tw * 8 + (lr & 7);
        *(float4*)&sOff[lr * 72 + f4 * 4] =
            *(const float4*)&offw[((size_t)b * 4096 + yy * 64 + xx) * 288 +
                                  g * 72 + f4 * 4];
    }
    __syncthreads();

    // ---------------- P0b: S-GEMM (to regs) + geometry ---------------------
    f32x4 sreg[5];
    {
        short8v a = *(const short8v*)&sQ[wv_ * 16 + row][kb8 * 8];
#pragma unroll
        for (int nt = 0; nt < 5; ++nt) {
            int rr = nt * 16 + row; if (rr > 65) rr = 65;   // tail clamp
            short8v bf = *(const short8v*)&sK[rr][kb8 * 8];
            f32x4 z = {0.f, 0.f, 0.f, 0.f};
            sreg[nt] = __builtin_amdgcn_mfma_f32_16x16x32_bf16(a, bf, z, 0, 0, 0);
        }
    }
    for (int item = tid; item < 576; item += 256) {
        int px = item / 9, pt = item - (item / 9) * 9;
        int lx = px & 15, ly = px >> 4;
        int hup = th * 4 + ly, wup = tw * 16 + lx;
        int lr = (ly >> 1) * 8 + (lx >> 1);
        int ij = ((hup & 1) << 1) | (wup & 1);
        float offy = sOff[lr * 72 + pt * 8 + ij];
        float offx = sOff[lr * 72 + pt * 8 + 4 + ij];
        float py  = offy + hup * 0.5f - 0.25f;
        float pxx = offx + wup * 0.5f - 0.25f;
        float y0f = floorf(py), x0f = floorf(pxx);
        float ty = py - y0f, tx = pxx - x0f;
        int y0 = (int)y0f, x0 = (int)x0f;
        int mk = 0;
        if ((unsigned)y0 < 64u && (unsigned)x0 < 64u)         mk |= 1;
        if ((unsigned)y0 < 64u && (unsigned)(x0+1) < 64u)     mk |= 2;
        if ((unsigned)(y0+1) < 64u && (unsigned)x0 < 64u)     mk |= 4;
        if ((unsigned)(y0+1) < 64u && (unsigned)(x0+1) < 64u) mk |= 8;
        int iy = y0 - ry0, ix = x0 - rx0;
        bool inreg = ((unsigned)iy <= (unsigned)(RROWS - 2)) &&
                     ((unsigned)ix <= (unsigned)(RCOLS - 2));
        int fl, zp;
        if (!mk)        { fl = 16; zp = 0; }
        else if (inreg) { fl = mk | 16; zp = iy * RCOLS + ix; }
        else            { fl = mk; zp = (y0 + 1) * 66 + (x0 + 1); }
        sGt[item] = (uint)f2h(ty) | ((uint)f2h(tx) << 16);
        sGz[item] = (zp << 5) | fl;
    }
    __syncthreads();

    // ---------------- P1: store S as fp16 (overwrites sOff) ----------------
#pragma unroll
    for (int nt = 0; nt < 5; ++nt) {
        int rp = nt * 16 + row;
        if (rp < RPX) {
#pragma unroll
            for (int r = 0; r < 4; ++r)
                sSW[wv_ * 16 + kb8 * 4 + r][rp] = f2h(sreg[nt][r]);
        }
    }
    __syncthreads();

    // ---------------- P2: attention logits ---------------------------------
    for (int item = tid; item < 576; item += 256) {
        int px = item / 9;
        uint gt = sGt[item];
        float ty = h2f((ushort)gt), tx = h2f((ushort)(gt >> 16));
        int z = sGz[item];
        int fl = z & 31;
        float a;
        if (fl & 16) {
            int zi = z >> 5;
            float w00 = (1.f - ty) * (1.f - tx), w01 = (1.f - ty) * tx;
            float w10 = ty * (1.f - tx), w11 = ty * tx;
            a  = (fl & 1) ? w00 * h2f(sSW[px][zi])             : 0.f;
            a += (fl & 2) ? w01 * h2f(sSW[px][zi + 1])         : 0.f;
            a += (fl & 4) ? w10 * h2f(sSW[px][zi + RCOLS])     : 0.f;
            a += (fl & 8) ? w11 * h2f(sSW[px][zi + RCOLS + 1]) : 0.f;
        } else {
            int t = z >> 5;
            int y0 = t / 66 - 1, x0 = t - (t / 66) * 66 - 1;
            a = 0.f;
#pragma unroll
            for (int c = 0; c < 4; ++c) if ((fl >> c) & 1) {
                int dy = c >> 1, dx = c & 1;
                float wgt = (dy ? ty : 1.f - ty) * (dx ? tx : 1.f - tx);
                const ushort* kr = &kbf[((size_t)b * 4096 + (y0 + dy) * 64 + x0 + dx) * 128 +
                                        g * EMB];
                float dot = 0.f;
                for (int e = 0; e < EMB; ++e) dot += bf2f(sQ[px][e]) * bf2f(kr[e]);
                a += wgt * dot;
            }
            int old = atomicAdd(&sFB[0], 1);
            if (old < 128) sFB[1 + old] = item;
        }
        sAttn[item] = a;
    }
    __syncthreads();

    // ---------------- P3: softmax (tid<64)  |  zero W (tid>=64) ------------
    if (tid < 64) {
        float aa[NPT];
        float mx = -1e30f;
#pragma unroll
        for (int p = 0; p < NPT; ++p) { aa[p] = sAttn[tid * 9 + p]; mx = fmaxf(mx, aa[p]); }
        float s = 0.f;
#pragma unroll
        for (int p = 0; p < NPT; ++p) { aa[p] = __expf(aa[p] - mx); s += aa[p]; }
        float inv = 1.f / s;
#pragma unroll
        for (int p = 0; p < NPT; ++p) sAttn[tid * 9 + p] = aa[p] * inv;
    } else {
        float4* p = (float4*)&sSW[0][0];
        float4 z4 = make_float4(0.f, 0.f, 0.f, 0.f);
        for (int i = tid - 64; i < 576; i += 192) p[i] = z4;
    }
    __syncthreads();

    // ---------------- P4: W-build (tid<64, serial fp16 RMW) ----------------
    if (tid < 64) {
        int px = tid;
#pragma unroll
        for (int pt = 0; pt < NPT; ++pt) {
            int item = px * 9 + pt;
            int z = sGz[item];
            int fl = z & 31;
            if (!(fl & 16)) continue;
            uint gt = sGt[item];
            float ty = h2f((ushort)gt), tx = h2f((ushort)(gt >> 16));
            float a = sAttn[item];
            int zi = z >> 5;
            ushort* c = &sSW[px][zi];
            if (fl & 1) c[0]         = f2h(h2f(c[0])         + (1.f-ty)*(1.f-tx)*a);
            if (fl & 2) c[1]         = f2h(h2f(c[1])         + (1.f-ty)*tx*a);
            if (fl & 4) c[RCOLS]     = f2h(h2f(c[RCOLS])     + ty*(1.f-tx)*a);
            if (fl & 8) c[RCOLS + 1] = f2h(h2f(c[RCOLS + 1]) + ty*tx*a);
        }
    }
    __syncthreads();

    // ---------------- P5: O-GEMM (f16 MFMA, K=64) + rp64/65 fix + store ----
    {
        half8v bfm[2][4];
#pragma unroll
        for (int kt = 0; kt < 2; ++kt)
#pragma unroll
            for (int nt = 0; nt < 4; ++nt)
                bfm[kt][nt] = *(const half8v*)&sXt[nt * 16 + row][kt * 32 + kb8 * 8];

        int px = wv_ * 16 + row;
        half8v af0 = *(const half8v*)&sSW[px][kb8 * 8];
        half8v af1 = *(const half8v*)&sSW[px][32 + kb8 * 8];

        f32x4 acc[4];
#pragma unroll
        for (int nt = 0; nt < 4; ++nt) { f32x4 z = {0.f,0.f,0.f,0.f}; acc[nt] = z; }
#pragma unroll
        for (int nt = 0; nt < 4; ++nt) {
            acc[nt] = __builtin_amdgcn_mfma_f32_16x16x32_f16(af0, bfm[0][nt], acc[nt], 0, 0, 0);
            acc[nt] = __builtin_amdgcn_mfma_f32_16x16x32_f16(af1, bfm[1][nt], acc[nt], 0, 0, 0);
        }
        // correction for K columns 64,65 (W cols 64-65 x X cols 64-65)
        float wc[4][2];
#pragma unroll
        for (int r = 0; r < 4; ++r) {
            uint u = *(uint*)&sSW[wv_ * 16 + kb8 * 4 + r][64];
            wc[r][0] = h2f((ushort)u); wc[r][1] = h2f((ushort)(u >> 16));
        }
#pragma unroll
        for (int nt = 0; nt < 4; ++nt) {
            uint u = *(uint*)&sXt[nt * 16 + row][64];
            float x0 = h2f((ushort)u), x1 = h2f((ushort)(u >> 16));
#pragma unroll
            for (int r = 0; r < 4; ++r)
                acc[nt][r] += wc[r][0] * x0 + wc[r][1] * x1;
        }
        int hup = th * 4 + wv_;
#pragma unroll
        for (int nt = 0; nt < 4; ++nt) {
            int ch = nt * 16 + row;
            float* ob = out + ((size_t)b * 256 + g * CGRP + ch) * 16384 +
                        hup * 128 + tw * 16 + kb8 * 4;
#pragma unroll
            for (int r = 0; r < 4; ++r) ob[r] = acc[nt][r];
        }
    }
    __syncthreads();

    // ---------------- P6: rare out-of-region fallback -----------------------
    int nfb = min(sFB[0], 128);
    for (int i = 0; i < nfb; ++i) {
        if (tid < 64) {
            int item = sFB[1 + i];
            int px = item / 9;
            uint gt = sGt[item];
            float ty = h2f((ushort)gt), tx = h2f((ushort)(gt >> 16));
            int z = sGz[item];
            float a = sAttn[item];
            int fl = z & 15;
            int t = z >> 5;
            int y0 = t / 66 - 1, x0 = t - (t / 66) * 66 - 1;
            const float* xg = x + ((size_t)b * 256 + g * CGRP + tid) * 4096;
            float v = 0.f;
            if (fl & 1) v += (1.f-ty)*(1.f-tx)*a * xg[y0*64 + x0];
            if (fl & 2) v += (1.f-ty)*tx*a       * xg[y0*64 + x0 + 1];
            if (fl & 4) v += ty*(1.f-tx)*a       * xg[(y0+1)*64 + x0];
            if (fl & 8) v += ty*tx*a             * xg[(y0+1)*64 + x0 + 1];
            int hup = th * 4 + (px >> 4), wup = tw * 16 + (px & 15);
            float* op = out + ((size_t)b * 256 + g * CGRP + tid) * 16384 +
                        hup * 128 + wup;
            *op += v;
        }
    }
}

// ---------------------------------------------------------------------------
extern "C" void kernel_launch(void* const* d_in, const int* in_sizes, int n_in,
                              void* d_out, int out_size, void* d_ws, size_t ws_size,
                              hipStream_t stream)
{
    const float* y    = (const float*)d_in[0];
    const float* x    = (const float*)d_in[1];
    const float* Wq   = (const float*)d_in[2];
    const float* bq   = (const float*)d_in[3];
    const float* Wk   = (const float*)d_in[4];
    const float* bk   = (const float*)d_in[5];
    const float* Woff = (const float*)d_in[6];
    const float* boff = (const float*)d_in[7];
    float* out = (float*)d_out;

    // workspace layout (~19.9 MB total)
    ushort* qbf   = (ushort*)d_ws;                            // 2*16384*128
    ushort* kbf   = qbf + (size_t)B_N * 16384 * 128;          // 2*4096*128
    float*  offw  = (float*)(kbf + (size_t)B_N * 4096 * 128); // 2*4096*288

    // both convs in one pipelined launch (weights converted in-kernel)
    mfma_gemm<<<dim3(1024), dim3(256), 0, stream>>>(
        y, x, Wq, Wk, Woff, bq, bk, boff, qbf, kbf, offw);

    // fused deformable attention
    deform_kernel<<<dim3(2048), dim3(256), 0, stream>>>(qbf, kbf, offw, x, out);
}

// Round 16
// 61.513 us; speedup vs baseline: 1.2639x; 1.0247x over previous
//
#include <hip/hip_runtime.h>

// Problem constants
#define B_N   2
#define H_LR  64
#define W_LR  64
#define HUP   128
#define WUP   128
#define GRP   4
#define NPT   9
#define EMB   32
#define CGRP  64
#define KIN   256
#define GE    128
#define NOFF  288

typedef __attribute__((ext_vector_type(8))) short short8v;
typedef _Float16 half8v __attribute__((ext_vector_type(8)));
typedef __attribute__((ext_vector_type(4))) float f32x4;

__device__ __forceinline__ ushort f2bf(float f) {
    unsigned u = __float_as_uint(f);
    u += 0x7FFFu + ((u >> 16) & 1u);
    return (ushort)(u >> 16);
}
__device__ __forceinline__ float bf2f(ushort h) {
    return __uint_as_float(((unsigned)h) << 16);
}
__device__ __forceinline__ ushort f2h(float f) {
    _Float16 h = (_Float16)f;
    return __builtin_bit_cast(ushort, h);
}
__device__ __forceinline__ float h2f(ushort u) {
    _Float16 h = __builtin_bit_cast(_Float16, u);
    return (float)h;
}

// ---------------------------------------------------------------------------
// Merged bf16 MFMA GEMM for both 1x1 convs, register-prefetch pipelined.
// Offsets now written as fp16 (halves off-path HBM traffic).
// blocks [0,512):   q  = Wq@y+bq    M=16384, BM=64, BN=128 (1 ntile)
// blocks [512,1024): koff = [Wk;Woff]@x+b  M=4096, BM=64, 4 ntiles of 128
// ---------------------------------------------------------------------------
__global__ __launch_bounds__(256, 4) void mfma_gemm(
    const float* __restrict__ y, const float* __restrict__ x,
    const float* __restrict__ Wq, const float* __restrict__ Wk,
    const float* __restrict__ Woff,
    const float* __restrict__ bq, const float* __restrict__ bk,
    const float* __restrict__ boff,
    ushort* __restrict__ qbf, ushort* __restrict__ kbf,
    ushort* __restrict__ offh)
{
    __shared__ __align__(16) ushort sY[64][68];
    __shared__ __align__(16) ushort sB[128][72];

    int bid = blockIdx.x;
    const float* SRC; const float* ba; const float* bb;
    ushort* OBF; ushort* OFH;
    int M, m0, n0, b;
    bool isQ = (bid < 512);
    if (isQ) {
        int mt = bid & 255; b = bid >> 8;
        SRC = y; ba = bq; bb = nullptr; OBF = qbf; OFH = nullptr;
        M = 16384; m0 = mt * 64; n0 = 0;
    } else {
        int r = bid - 512;
        int mt = r & 63, nt2 = (r >> 6) & 3; b = r >> 8;
        SRC = x; ba = bk; bb = boff; OBF = kbf; OFH = offh;
        M = 4096; m0 = mt * 64; n0 = nt2 * 128;
    }

    int tid = threadIdx.x;
    int lane = tid & 63;
    int wv = tid >> 6, wm = wv >> 1, wn = wv & 1;
    int il = lane & 15, g4 = lane >> 4;
    int st_m4 = tid & 15, st_c = tid >> 4;
    int st_c8 = tid & 7,  st_n = tid >> 3;

    const float* wrowp[4];
#pragma unroll
    for (int i = 0; i < 4; ++i) {
        int n = n0 + st_n + i * 32;
        if (isQ)            wrowp[i] = Wq  + (size_t)n * KIN;
        else if (n < GE)    wrowp[i] = Wk  + (size_t)n * KIN;
        else if (n < GE + NOFF) wrowp[i] = Woff + (size_t)(n - GE) * KIN;
        else                wrowp[i] = nullptr;
    }

    f32x4 acc[2][4];
#pragma unroll
    for (int i = 0; i < 2; ++i)
#pragma unroll
        for (int j = 0; j < 4; ++j) { f32x4 z = {0.f,0.f,0.f,0.f}; acc[i][j] = z; }

    const float* src_b = SRC + (size_t)b * KIN * M;

    float4 ra[4]; short8v rb[4];
#pragma unroll
    for (int i = 0; i < 4; ++i)
        ra[i] = *(const float4*)&src_b[(size_t)(st_c + i * 16) * M + m0 + st_m4 * 4];
#pragma unroll
    for (int i = 0; i < 4; ++i) {
        short8v t = {0,0,0,0,0,0,0,0};
        if (wrowp[i]) {
            float4 a = *(const float4*)&wrowp[i][st_c8 * 8];
            float4 c = *(const float4*)&wrowp[i][st_c8 * 8 + 4];
            t[0]=(short)f2bf(a.x); t[1]=(short)f2bf(a.y); t[2]=(short)f2bf(a.z); t[3]=(short)f2bf(a.w);
            t[4]=(short)f2bf(c.x); t[5]=(short)f2bf(c.y); t[6]=(short)f2bf(c.z); t[7]=(short)f2bf(c.w);
        }
        rb[i] = t;
    }

    for (int ks = 0; ks < 4; ++ks) {
#pragma unroll
        for (int i = 0; i < 4; ++i) {
            ushort4 h;
            h.x = f2bf(ra[i].x); h.y = f2bf(ra[i].y);
            h.z = f2bf(ra[i].z); h.w = f2bf(ra[i].w);
            *(ushort4*)&sY[st_c + i * 16][st_m4 * 4] = h;
            *(short8v*)&sB[st_n + i * 32][st_c8 * 8] = rb[i];
        }
        __syncthreads();
        if (ks < 3) {
            int k0 = (ks + 1) * 64;
#pragma unroll
            for (int i = 0; i < 4; ++i)
                ra[i] = *(const float4*)&src_b[(size_t)(k0 + st_c + i * 16) * M + m0 + st_m4 * 4];
#pragma unroll
            for (int i = 0; i < 4; ++i) {
                short8v t = {0,0,0,0,0,0,0,0};
                if (wrowp[i]) {
                    float4 a = *(const float4*)&wrowp[i][k0 + st_c8 * 8];
                    float4 c = *(const float4*)&wrowp[i][k0 + st_c8 * 8 + 4];
                    t[0]=(short)f2bf(a.x); t[1]=(short)f2bf(a.y); t[2]=(short)f2bf(a.z); t[3]=(short)f2bf(a.w);
                    t[4]=(short)f2bf(c.x); t[5]=(short)f2bf(c.y); t[6]=(short)f2bf(c.z); t[7]=(short)f2bf(c.w);
                }
                rb[i] = t;
            }
        }
#pragma unroll
        for (int kc = 0; kc < 2; ++kc) {
            int kb = kc * 32 + g4 * 8;
            short8v af[2], bfr[4];
#pragma unroll
            for (int mf = 0; mf < 2; ++mf) {
                int m = wm * 32 + mf * 16 + il;
                short8v t;
#pragma unroll
                for (int j = 0; j < 8; ++j) t[j] = (short)sY[kb + j][m];
                af[mf] = t;
            }
#pragma unroll
            for (int nf = 0; nf < 4; ++nf)
                bfr[nf] = *(const short8v*)&sB[wn * 64 + nf * 16 + il][kb];
#pragma unroll
            for (int mf = 0; mf < 2; ++mf)
#pragma unroll
                for (int nf = 0; nf < 4; ++nf)
                    acc[mf][nf] = __builtin_amdgcn_mfma_f32_16x16x32_bf16(
                        af[mf], bfr[nf], acc[mf][nf], 0, 0, 0);
        }
        __syncthreads();
    }

#pragma unroll
    for (int mf = 0; mf < 2; ++mf) {
#pragma unroll
        for (int r = 0; r < 4; ++r) {
            int m = m0 + wm * 32 + mf * 16 + g4 * 4 + r;
            size_t row = (size_t)b * M + m;
#pragma unroll
            for (int nf = 0; nf < 4; ++nf) {
                int n = n0 + wn * 64 + nf * 16 + il;
                float v = acc[mf][nf][r];
                if (n < GE) {
                    OBF[row * 128 + n] = f2bf(v + ba[n]);
                } else {
                    int no = n - GE;
                    if (no < NOFF) OFH[row * 288 + no] = f2h(v + bb[no]);
                }
            }
        }
    }
}

// ---------------------------------------------------------------------------
// Fused deformable attention via per-block dense MFMA GEMMs.
// Best-measured structure (round 15, 63.03 us) with fp16 offsets:
// XCD-aware remap; offsets staged as fp16 into the first 16 rows of sSW.
// ---------------------------------------------------------------------------
#define RROWS 6
#define RCOLS 11
#define RPX   66

__global__ __launch_bounds__(256, 4) void deform_kernel(
    const ushort* __restrict__ qbf,  // [B, 16384, 128] bf16 pixel-major
    const ushort* __restrict__ kbf,  // [B, 4096, 128] bf16 pixel-major
    const ushort* __restrict__ offh, // [B, 4096, 288] fp16 pixel-major
    const float* __restrict__ x,     // [B, 256, 64, 64] channel-major (input)
    float* __restrict__ out)         // [B, 256, 128, 128]
{
    __shared__ __align__(16) ushort sXt[64][72];  // x region fp16 [ch][rp 0..65]
    __shared__ __align__(16) ushort sK[66][40];   // k region bf16
    __shared__ __align__(16) ushort sQ[64][40];   // q bf16
    __shared__ __align__(16) ushort sSW[64][72];  // P0: off fp16 (rows 0..15); P1+: S then W fp16
    __shared__ uint   sGt[576];                   // packed {ty,tx} fp16
    __shared__ int    sGz[576];                   // packed zi + flags
    __shared__ float  sAttn[576];                 // logits -> normalized attn
    __shared__ int    sFB[129];                   // fallback list

    int bxl = blockIdx.x;
    // XCD-aware remap (bijective, 2048 % 8 == 0): XCD k <- one (b,g) pair
    int bx = (bxl & 7) * 256 + (bxl >> 3);
    int tw = bx & 7, th = (bx >> 3) & 31, g = (bx >> 8) & 3, b = bx >> 10;
    int tid = threadIdx.x;
    int wv_ = tid >> 6, lane = tid & 63;
    int row = lane & 15, kb8 = lane >> 4;

    const int ry0 = th * 2 - 2, rx0 = tw * 8 - 1;

    // ---------------- P0a: all staging (coalesced) -------------------------
    if (tid == 0) sFB[0] = 0;
    // x region -> fp16, pair-packed u32 stores
    for (int s = tid; s < 384; s += 256) {
        int gy = s % 6, ch = s / 6;
        int gyg = min(max(ry0 + gy, 0), 63);
        const float* xr = x + ((size_t)b * 256 + g * CGRP + ch) * 4096 + gyg * 64;
        float v[11];
        if (tw >= 1 && tw <= 6) {
            int a0 = rx0 - 3;                    // 16B-aligned, in-bounds
            float tmp[16];
#pragma unroll
            for (int t4 = 0; t4 < 4; ++t4) {
                float4 f = *(const float4*)&xr[a0 + t4 * 4];
                tmp[t4*4+0] = f.x; tmp[t4*4+1] = f.y; tmp[t4*4+2] = f.z; tmp[t4*4+3] = f.w;
            }
#pragma unroll
            for (int qx = 0; qx < RCOLS; ++qx) v[qx] = tmp[qx + 3];
        } else {
#pragma unroll
            for (int qx = 0; qx < RCOLS; ++qx) {
                int gxg = min(max(rx0 + qx, 0), 63);
                v[qx] = xr[gxg];
            }
        }
        ushort* dst = &sXt[ch][0];
        int c0 = gy * RCOLS;
        if (c0 & 1) {
            dst[c0] = f2h(v[0]);
#pragma unroll
            for (int j = 0; j < 5; ++j)
                *(uint*)&dst[c0 + 1 + 2*j] =
                    (uint)f2h(v[1 + 2*j]) | ((uint)f2h(v[2 + 2*j]) << 16);
        } else {
#pragma unroll
            for (int j = 0; j < 5; ++j)
                *(uint*)&dst[c0 + 2*j] =
                    (uint)f2h(v[2*j]) | ((uint)f2h(v[1 + 2*j]) << 16);
            dst[c0 + 10] = f2h(v[10]);
        }
    }
    // k region bf16
    for (int i = tid; i < 264; i += 256) {
        int rp = i >> 2, c4 = i & 3;
        int qy = rp / RCOLS, qx = rp - qy * RCOLS;
        int gy = min(max(ry0 + qy, 0), 63), gx = min(max(rx0 + qx, 0), 63);
        *(short8v*)&sK[rp][c4 * 8] =
            *(const short8v*)&kbf[((size_t)b * 4096 + gy * 64 + gx) * 128 +
                                  g * EMB + c4 * 8];
    }
    // q bf16
    {
        int px = tid >> 2, c4 = tid & 3;
        int hup = th * 4 + (px >> 4), wup = tw * 16 + (px & 15);
        *(short8v*)&sQ[px][c4 * 8] =
            *(const short8v*)&qbf[((size_t)b * 16384 + hup * 128 + wup) * 128 +
                                  g * EMB + c4 * 8];
    }
    // offsets (fp16, coalesced short8v) -> sSW rows 0..15
    for (int i = tid; i < 144; i += 256) {
        int lr = i / 9, f8 = i - (i / 9) * 9;
        int yy = th * 2 + (lr >> 3), xx = tw * 8 + (lr & 7);
        *(short8v*)&sSW[lr][f8 * 8] =
            *(const short8v*)&offh[((size_t)b * 4096 + yy * 64 + xx) * 288 +
                                   g * 72 + f8 * 8];
    }
    __syncthreads();

    // ---------------- P0b: S-GEMM (to regs) + geometry ---------------------
    f32x4 sreg[5];
    {
        short8v a = *(const short8v*)&sQ[wv_ * 16 + row][kb8 * 8];
#pragma unroll
        for (int nt = 0; nt < 5; ++nt) {
            int rr = nt * 16 + row; if (rr > 65) rr = 65;   // tail clamp
            short8v bf = *(const short8v*)&sK[rr][kb8 * 8];
            f32x4 z = {0.f, 0.f, 0.f, 0.f};
            sreg[nt] = __builtin_amdgcn_mfma_f32_16x16x32_bf16(a, bf, z, 0, 0, 0);
        }
    }
    for (int item = tid; item < 576; item += 256) {
        int px = item / 9, pt = item - (item / 9) * 9;
        int lx = px & 15, ly = px >> 4;
        int hup = th * 4 + ly, wup = tw * 16 + lx;
        int lr = (ly >> 1) * 8 + (lx >> 1);
        int ij = ((hup & 1) << 1) | (wup & 1);
        float offy = h2f(sSW[lr][pt * 8 + ij]);
        float offx = h2f(sSW[lr][pt * 8 + 4 + ij]);
        float py  = offy + hup * 0.5f - 0.25f;
        float pxx = offx + wup * 0.5f - 0.25f;
        float y0f = floorf(py), x0f = floorf(pxx);
        float ty = py - y0f, tx = pxx - x0f;
        int y0 = (int)y0f, x0 = (int)x0f;
        int mk = 0;
        if ((unsigned)y0 < 64u && (unsigned)x0 < 64u)         mk |= 1;
        if ((unsigned)y0 < 64u && (unsigned)(x0+1) < 64u)     mk |= 2;
        if ((unsigned)(y0+1) < 64u && (unsigned)x0 < 64u)     mk |= 4;
        if ((unsigned)(y0+1) < 64u && (unsigned)(x0+1) < 64u) mk |= 8;
        int iy = y0 - ry0, ix = x0 - rx0;
        bool inreg = ((unsigned)iy <= (unsigned)(RROWS - 2)) &&
                     ((unsigned)ix <= (unsigned)(RCOLS - 2));
        int fl, zp;
        if (!mk)        { fl = 16; zp = 0; }
        else if (inreg) { fl = mk | 16; zp = iy * RCOLS + ix; }
        else            { fl = mk; zp = (y0 + 1) * 66 + (x0 + 1); }
        sGt[item] = (uint)f2h(ty) | ((uint)f2h(tx) << 16);
        sGz[item] = (zp << 5) | fl;
    }
    __syncthreads();

    // ---------------- P1: store S as fp16 (overwrites offsets) -------------
#pragma unroll
    for (int nt = 0; nt < 5; ++nt) {
        int rp = nt * 16 + row;
        if (rp < RPX) {
#pragma unroll
            for (int r = 0; r < 4; ++r)
                sSW[wv_ * 16 + kb8 * 4 + r][rp] = f2h(sreg[nt][r]);
        }
    }
    __syncthreads();

    // ---------------- P2: attention logits ---------------------------------
    for (int item = tid; item < 576; item += 256) {
        int px = item / 9;
        uint gt = sGt[item];
        float ty = h2f((ushort)gt), tx = h2f((ushort)(gt >> 16));
        int z = sGz[item];
        int fl = z & 31;
        float a;
        if (fl & 16) {
            int zi = z >> 5;
            float w00 = (1.f - ty) * (1.f - tx), w01 = (1.f - ty) * tx;
            float w10 = ty * (1.f - tx), w11 = ty * tx;
            a  = (fl & 1) ? w00 * h2f(sSW[px][zi])             : 0.f;
            a += (fl & 2) ? w01 * h2f(sSW[px][zi + 1])         : 0.f;
            a += (fl & 4) ? w10 * h2f(sSW[px][zi + RCOLS])     : 0.f;
            a += (fl & 8) ? w11 * h2f(sSW[px][zi + RCOLS + 1]) : 0.f;
        } else {
            int t = z >> 5;
            int y0 = t / 66 - 1, x0 = t - (t / 66) * 66 - 1;
            a = 0.f;
#pragma unroll
            for (int c = 0; c < 4; ++c) if ((fl >> c) & 1) {
                int dy = c >> 1, dx = c & 1;
                float wgt = (dy ? ty : 1.f - ty) * (dx ? tx : 1.f - tx);
                const ushort* kr = &kbf[((size_t)b * 4096 + (y0 + dy) * 64 + x0 + dx) * 128 +
                                        g * EMB];
                float dot = 0.f;
                for (int e = 0; e < EMB; ++e) dot += bf2f(sQ[px][e]) * bf2f(kr[e]);
                a += wgt * dot;
            }
            int old = atomicAdd(&sFB[0], 1);
            if (old < 128) sFB[1 + old] = item;
        }
        sAttn[item] = a;
    }
    __syncthreads();

    // ---------------- P3: softmax (tid<64)  |  zero W (tid>=64) ------------
    if (tid < 64) {
        float aa[NPT];
        float mx = -1e30f;
#pragma unroll
        for (int p = 0; p < NPT; ++p) { aa[p] = sAttn[tid * 9 + p]; mx = fmaxf(mx, aa[p]); }
        float s = 0.f;
#pragma unroll
        for (int p = 0; p < NPT; ++p) { aa[p] = __expf(aa[p] - mx); s += aa[p]; }
        float inv = 1.f / s;
#pragma unroll
        for (int p = 0; p < NPT; ++p) sAttn[tid * 9 + p] = aa[p] * inv;
    } else {
        float4* p = (float4*)&sSW[0][0];
        float4 z4 = make_float4(0.f, 0.f, 0.f, 0.f);
        for (int i = tid - 64; i < 576; i += 192) p[i] = z4;
    }
    __syncthreads();

    // ---------------- P4: W-build (tid<64, serial fp16 RMW) ----------------
    if (tid < 64) {
        int px = tid;
#pragma unroll
        for (int pt = 0; pt < NPT; ++pt) {
            int item = px * 9 + pt;
            int z = sGz[item];
            int fl = z & 31;
            if (!(fl & 16)) continue;
            uint gt = sGt[item];
            float ty = h2f((ushort)gt), tx = h2f((ushort)(gt >> 16));
            float a = sAttn[item];
            int zi = z >> 5;
            ushort* c = &sSW[px][zi];
            if (fl & 1) c[0]         = f2h(h2f(c[0])         + (1.f-ty)*(1.f-tx)*a);
            if (fl & 2) c[1]         = f2h(h2f(c[1])         + (1.f-ty)*tx*a);
            if (fl & 4) c[RCOLS]     = f2h(h2f(c[RCOLS])     + ty*(1.f-tx)*a);
            if (fl & 8) c[RCOLS + 1] = f2h(h2f(c[RCOLS + 1]) + ty*tx*a);
        }
    }
    __syncthreads();

    // ---------------- P5: O-GEMM (f16 MFMA, K=64) + rp64/65 fix + store ----
    {
        half8v bfm[2][4];
#pragma unroll
        for (int kt = 0; kt < 2; ++kt)
#pragma unroll
            for (int nt = 0; nt < 4; ++nt)
                bfm[kt][nt] = *(const half8v*)&sXt[nt * 16 + row][kt * 32 + kb8 * 8];

        int px = wv_ * 16 + row;
        half8v af0 = *(const half8v*)&sSW[px][kb8 * 8];
        half8v af1 = *(const half8v*)&sSW[px][32 + kb8 * 8];

        f32x4 acc[4];
#pragma unroll
        for (int nt = 0; nt < 4; ++nt) { f32x4 z = {0.f,0.f,0.f,0.f}; acc[nt] = z; }
#pragma unroll
        for (int nt = 0; nt < 4; ++nt) {
            acc[nt] = __builtin_amdgcn_mfma_f32_16x16x32_f16(af0, bfm[0][nt], acc[nt], 0, 0, 0);
            acc[nt] = __builtin_amdgcn_mfma_f32_16x16x32_f16(af1, bfm[1][nt], acc[nt], 0, 0, 0);
        }
        // correction for K columns 64,65 (W cols 64-65 x X cols 64-65)
        float wc[4][2];
#pragma unroll
        for (int r = 0; r < 4; ++r) {
            uint u = *(uint*)&sSW[wv_ * 16 + kb8 * 4 + r][64];
            wc[r][0] = h2f((ushort)u); wc[r][1] = h2f((ushort)(u >> 16));
        }
#pragma unroll
        for (int nt = 0; nt < 4; ++nt) {
            uint u = *(uint*)&sXt[nt * 16 + row][64];
            float x0 = h2f((ushort)u), x1 = h2f((ushort)(u >> 16));
#pragma unroll
            for (int r = 0; r < 4; ++r)
                acc[nt][r] += wc[r][0] * x0 + wc[r][1] * x1;
        }
        int hup = th * 4 + wv_;
#pragma unroll
        for (int nt = 0; nt < 4; ++nt) {
            int ch = nt * 16 + row;
            float* ob = out + ((size_t)b * 256 + g * CGRP + ch) * 16384 +
                        hup * 128 + tw * 16 + kb8 * 4;
#pragma unroll
            for (int r = 0; r < 4; ++r) ob[r] = acc[nt][r];
        }
    }
    __syncthreads();

    // ---------------- P6: rare out-of-region fallback -----------------------
    int nfb = min(sFB[0], 128);
    for (int i = 0; i < nfb; ++i) {
        if (tid < 64) {
            int item = sFB[1 + i];
            int px = item / 9;
            uint gt = sGt[item];
            float ty = h2f((ushort)gt), tx = h2f((ushort)(gt >> 16));
            int z = sGz[item];
            float a = sAttn[item];
            int fl = z & 15;
            int t = z >> 5;
            int y0 = t / 66 - 1, x0 = t - (t / 66) * 66 - 1;
            const float* xg = x + ((size_t)b * 256 + g * CGRP + tid) * 4096;
            float v = 0.f;
            if (fl & 1) v += (1.f-ty)*(1.f-tx)*a * xg[y0*64 + x0];
            if (fl & 2) v += (1.f-ty)*tx*a       * xg[y0*64 + x0 + 1];
            if (fl & 4) v += ty*(1.f-tx)*a       * xg[(y0+1)*64 + x0];
            if (fl & 8) v += ty*tx*a             * xg[(y0+1)*64 + x0 + 1];
            int hup = th * 4 + (px >> 4), wup = tw * 16 + (px & 15);
            float* op = out + ((size_t)b * 256 + g * CGRP + tid) * 16384 +
                        hup * 128 + wup;
            *op += v;
        }
    }
}

// ---------------------------------------------------------------------------
extern "C" void kernel_launch(void* const* d_in, const int* in_sizes, int n_in,
                              void* d_out, int out_size, void* d_ws, size_t ws_size,
                              hipStream_t stream)
{
    const float* y    = (const float*)d_in[0];
    const float* x    = (const float*)d_in[1];
    const float* Wq   = (const float*)d_in[2];
    const float* bq   = (const float*)d_in[3];
    const float* Wk   = (const float*)d_in[4];
    const float* bk   = (const float*)d_in[5];
    const float* Woff = (const float*)d_in[6];
    const float* boff = (const float*)d_in[7];
    float* out = (float*)d_out;

    // workspace layout (~15.2 MB total)
    ushort* qbf   = (ushort*)d_ws;                            // 2*16384*128
    ushort* kbf   = qbf + (size_t)B_N * 16384 * 128;          // 2*4096*128
    ushort* offh  = kbf + (size_t)B_N * 4096 * 128;           // 2*4096*288 fp16

    // both convs in one pipelined launch (weights converted in-kernel)
    mfma_gemm<<<dim3(1024), dim3(256), 0, stream>>>(
        y, x, Wq, Wk, Woff, bq, bk, boff, qbf, kbf, offh);

    // fused deformable attention
    deform_kernel<<<dim3(2048), dim3(256), 0, stream>>>(qbf, kbf, offh, x, out);
}

// Round 17
// 61.297 us; speedup vs baseline: 1.2683x; 1.0035x over previous
//
#include <hip/hip_runtime.h>

// Problem constants
#define B_N   2
#define H_LR  64
#define W_LR  64
#define HUP   128
#define WUP   128
#define GRP   4
#define NPT   9
#define EMB   32
#define CGRP  64
#define KIN   256
#define GE    128
#define NOFF  288

typedef __attribute__((ext_vector_type(8))) short short8v;
typedef _Float16 half8v __attribute__((ext_vector_type(8)));
typedef __attribute__((ext_vector_type(4))) float f32x4;

__device__ __forceinline__ ushort f2bf(float f) {
    unsigned u = __float_as_uint(f);
    u += 0x7FFFu + ((u >> 16) & 1u);
    return (ushort)(u >> 16);
}
__device__ __forceinline__ float bf2f(ushort h) {
    return __uint_as_float(((unsigned)h) << 16);
}
__device__ __forceinline__ ushort f2h(float f) {
    _Float16 h = (_Float16)f;
    return __builtin_bit_cast(ushort, h);
}
__device__ __forceinline__ float h2f(ushort u) {
    _Float16 h = __builtin_bit_cast(_Float16, u);
    return (float)h;
}

// ---------------------------------------------------------------------------
// Merged bf16 MFMA GEMM for both 1x1 convs, register-prefetch pipelined.
// (unchanged — frozen since round 15)
// ---------------------------------------------------------------------------
__global__ __launch_bounds__(256, 4) void mfma_gemm(
    const float* __restrict__ y, const float* __restrict__ x,
    const float* __restrict__ Wq, const float* __restrict__ Wk,
    const float* __restrict__ Woff,
    const float* __restrict__ bq, const float* __restrict__ bk,
    const float* __restrict__ boff,
    ushort* __restrict__ qbf, ushort* __restrict__ kbf,
    ushort* __restrict__ offh)
{
    __shared__ __align__(16) ushort sY[64][68];
    __shared__ __align__(16) ushort sB[128][72];

    int bid = blockIdx.x;
    const float* SRC; const float* ba; const float* bb;
    ushort* OBF; ushort* OFH;
    int M, m0, n0, b;
    bool isQ = (bid < 512);
    if (isQ) {
        int mt = bid & 255; b = bid >> 8;
        SRC = y; ba = bq; bb = nullptr; OBF = qbf; OFH = nullptr;
        M = 16384; m0 = mt * 64; n0 = 0;
    } else {
        int r = bid - 512;
        int mt = r & 63, nt2 = (r >> 6) & 3; b = r >> 8;
        SRC = x; ba = bk; bb = boff; OBF = kbf; OFH = offh;
        M = 4096; m0 = mt * 64; n0 = nt2 * 128;
    }

    int tid = threadIdx.x;
    int lane = tid & 63;
    int wv = tid >> 6, wm = wv >> 1, wn = wv & 1;
    int il = lane & 15, g4 = lane >> 4;
    int st_m4 = tid & 15, st_c = tid >> 4;
    int st_c8 = tid & 7,  st_n = tid >> 3;

    const float* wrowp[4];
#pragma unroll
    for (int i = 0; i < 4; ++i) {
        int n = n0 + st_n + i * 32;
        if (isQ)            wrowp[i] = Wq  + (size_t)n * KIN;
        else if (n < GE)    wrowp[i] = Wk  + (size_t)n * KIN;
        else if (n < GE + NOFF) wrowp[i] = Woff + (size_t)(n - GE) * KIN;
        else                wrowp[i] = nullptr;
    }

    f32x4 acc[2][4];
#pragma unroll
    for (int i = 0; i < 2; ++i)
#pragma unroll
        for (int j = 0; j < 4; ++j) { f32x4 z = {0.f,0.f,0.f,0.f}; acc[i][j] = z; }

    const float* src_b = SRC + (size_t)b * KIN * M;

    float4 ra[4]; short8v rb[4];
#pragma unroll
    for (int i = 0; i < 4; ++i)
        ra[i] = *(const float4*)&src_b[(size_t)(st_c + i * 16) * M + m0 + st_m4 * 4];
#pragma unroll
    for (int i = 0; i < 4; ++i) {
        short8v t = {0,0,0,0,0,0,0,0};
        if (wrowp[i]) {
            float4 a = *(const float4*)&wrowp[i][st_c8 * 8];
            float4 c = *(const float4*)&wrowp[i][st_c8 * 8 + 4];
            t[0]=(short)f2bf(a.x); t[1]=(short)f2bf(a.y); t[2]=(short)f2bf(a.z); t[3]=(short)f2bf(a.w);
            t[4]=(short)f2bf(c.x); t[5]=(short)f2bf(c.y); t[6]=(short)f2bf(c.z); t[7]=(short)f2bf(c.w);
        }
        rb[i] = t;
    }

    for (int ks = 0; ks < 4; ++ks) {
#pragma unroll
        for (int i = 0; i < 4; ++i) {
            ushort4 h;
            h.x = f2bf(ra[i].x); h.y = f2bf(ra[i].y);
            h.z = f2bf(ra[i].z); h.w = f2bf(ra[i].w);
            *(ushort4*)&sY[st_c + i * 16][st_m4 * 4] = h;
            *(short8v*)&sB[st_n + i * 32][st_c8 * 8] = rb[i];
        }
        __syncthreads();
        if (ks < 3) {
            int k0 = (ks + 1) * 64;
#pragma unroll
            for (int i = 0; i < 4; ++i)
                ra[i] = *(const float4*)&src_b[(size_t)(k0 + st_c + i * 16) * M + m0 + st_m4 * 4];
#pragma unroll
            for (int i = 0; i < 4; ++i) {
                short8v t = {0,0,0,0,0,0,0,0};
                if (wrowp[i]) {
                    float4 a = *(const float4*)&wrowp[i][k0 + st_c8 * 8];
                    float4 c = *(const float4*)&wrowp[i][k0 + st_c8 * 8 + 4];
                    t[0]=(short)f2bf(a.x); t[1]=(short)f2bf(a.y); t[2]=(short)f2bf(a.z); t[3]=(short)f2bf(a.w);
                    t[4]=(short)f2bf(c.x); t[5]=(short)f2bf(c.y); t[6]=(short)f2bf(c.z); t[7]=(short)f2bf(c.w);
                }
                rb[i] = t;
            }
        }
#pragma unroll
        for (int kc = 0; kc < 2; ++kc) {
            int kb = kc * 32 + g4 * 8;
            short8v af[2], bfr[4];
#pragma unroll
            for (int mf = 0; mf < 2; ++mf) {
                int m = wm * 32 + mf * 16 + il;
                short8v t;
#pragma unroll
                for (int j = 0; j < 8; ++j) t[j] = (short)sY[kb + j][m];
                af[mf] = t;
            }
#pragma unroll
            for (int nf = 0; nf < 4; ++nf)
                bfr[nf] = *(const short8v*)&sB[wn * 64 + nf * 16 + il][kb];
#pragma unroll
            for (int mf = 0; mf < 2; ++mf)
#pragma unroll
                for (int nf = 0; nf < 4; ++nf)
                    acc[mf][nf] = __builtin_amdgcn_mfma_f32_16x16x32_bf16(
                        af[mf], bfr[nf], acc[mf][nf], 0, 0, 0);
        }
        __syncthreads();
    }

#pragma unroll
    for (int mf = 0; mf < 2; ++mf) {
#pragma unroll
        for (int r = 0; r < 4; ++r) {
            int m = m0 + wm * 32 + mf * 16 + g4 * 4 + r;
            size_t row = (size_t)b * M + m;
#pragma unroll
            for (int nf = 0; nf < 4; ++nf) {
                int n = n0 + wn * 64 + nf * 16 + il;
                float v = acc[mf][nf][r];
                if (n < GE) {
                    OBF[row * 128 + n] = f2bf(v + ba[n]);
                } else {
                    int no = n - GE;
                    if (no < NOFF) OFH[row * 288 + no] = f2h(v + bb[no]);
                }
            }
        }
    }
}

// ---------------------------------------------------------------------------
// Fused deformable attention via per-block dense MFMA GEMMs.
// Round-16 structure with the barrier chain compressed 7 -> 4(+1 rare):
//  - offsets staged into sAttn's storage (dead until P2) so S-MFMA stores
//    directly into sSW inside P0b (P1 phase deleted)
//  - P3+P4 merged: px-thread does softmax, zeroes own W row, builds it
//  - pre-P6 barrier only when fallback items exist
// ---------------------------------------------------------------------------
#define RROWS 6
#define RCOLS 11
#define RPX   66

__global__ __launch_bounds__(256, 4) void deform_kernel(
    const ushort* __restrict__ qbf,  // [B, 16384, 128] bf16 pixel-major
    const ushort* __restrict__ kbf,  // [B, 4096, 128] bf16 pixel-major
    const ushort* __restrict__ offh, // [B, 4096, 288] fp16 pixel-major
    const float* __restrict__ x,     // [B, 256, 64, 64] channel-major (input)
    float* __restrict__ out)         // [B, 256, 128, 128]
{
    __shared__ __align__(16) ushort sXt[64][72];  // x region fp16 [ch][rp 0..65]
    __shared__ __align__(16) ushort sK[66][40];   // k region bf16
    __shared__ __align__(16) ushort sQ[64][40];   // q bf16
    __shared__ __align__(16) ushort sSW[64][72];  // S then W fp16
    __shared__ uint   sGt[576];                   // packed {ty,tx} fp16
    __shared__ int    sGz[576];                   // packed zi + flags
    __shared__ __align__(16) float sAttn[576];    // P0: offsets fp16; P2+: logits/attn
    __shared__ int    sFB[129];                   // fallback list

    int bxl = blockIdx.x;
    // XCD-aware remap (bijective, 2048 % 8 == 0): XCD k <- one (b,g) pair
    int bx = (bxl & 7) * 256 + (bxl >> 3);
    int tw = bx & 7, th = (bx >> 3) & 31, g = (bx >> 8) & 3, b = bx >> 10;
    int tid = threadIdx.x;
    int wv_ = tid >> 6, lane = tid & 63;
    int row = lane & 15, kb8 = lane >> 4;

    const int ry0 = th * 2 - 2, rx0 = tw * 8 - 1;
    ushort* sOffA = (ushort*)sAttn;               // [16][72] fp16 offset slice

    // ---------------- P0a: all staging (coalesced) -------------------------
    if (tid == 0) sFB[0] = 0;
    // x region -> fp16, pair-packed u32 stores
    for (int s = tid; s < 384; s += 256) {
        int gy = s % 6, ch = s / 6;
        int gyg = min(max(ry0 + gy, 0), 63);
        const float* xr = x + ((size_t)b * 256 + g * CGRP + ch) * 4096 + gyg * 64;
        float v[11];
        if (tw >= 1 && tw <= 6) {
            int a0 = rx0 - 3;                    // 16B-aligned, in-bounds
            float tmp[16];
#pragma unroll
            for (int t4 = 0; t4 < 4; ++t4) {
                float4 f = *(const float4*)&xr[a0 + t4 * 4];
                tmp[t4*4+0] = f.x; tmp[t4*4+1] = f.y; tmp[t4*4+2] = f.z; tmp[t4*4+3] = f.w;
            }
#pragma unroll
            for (int qx = 0; qx < RCOLS; ++qx) v[qx] = tmp[qx + 3];
        } else {
#pragma unroll
            for (int qx = 0; qx < RCOLS; ++qx) {
                int gxg = min(max(rx0 + qx, 0), 63);
                v[qx] = xr[gxg];
            }
        }
        ushort* dst = &sXt[ch][0];
        int c0 = gy * RCOLS;
        if (c0 & 1) {
            dst[c0] = f2h(v[0]);
#pragma unroll
            for (int j = 0; j < 5; ++j)
                *(uint*)&dst[c0 + 1 + 2*j] =
                    (uint)f2h(v[1 + 2*j]) | ((uint)f2h(v[2 + 2*j]) << 16);
        } else {
#pragma unroll
            for (int j = 0; j < 5; ++j)
                *(uint*)&dst[c0 + 2*j] =
                    (uint)f2h(v[2*j]) | ((uint)f2h(v[1 + 2*j]) << 16);
            dst[c0 + 10] = f2h(v[10]);
        }
    }
    // k region bf16
    for (int i = tid; i < 264; i += 256) {
        int rp = i >> 2, c4 = i & 3;
        int qy = rp / RCOLS, qx = rp - qy * RCOLS;
        int gy = min(max(ry0 + qy, 0), 63), gx = min(max(rx0 + qx, 0), 63);
        *(short8v*)&sK[rp][c4 * 8] =
            *(const short8v*)&kbf[((size_t)b * 4096 + gy * 64 + gx) * 128 +
                                  g * EMB + c4 * 8];
    }
    // q bf16
    {
        int px = tid >> 2, c4 = tid & 3;
        int hup = th * 4 + (px >> 4), wup = tw * 16 + (px & 15);
        *(short8v*)&sQ[px][c4 * 8] =
            *(const short8v*)&qbf[((size_t)b * 16384 + hup * 128 + wup) * 128 +
                                  g * EMB + c4 * 8];
    }
    // offsets (fp16, coalesced short8v) -> sOffA (aliases sAttn; dead till P2)
    for (int i = tid; i < 144; i += 256) {
        int lr = i / 9, f8 = i - (i / 9) * 9;
        int yy = th * 2 + (lr >> 3), xx = tw * 8 + (lr & 7);
        *(short8v*)&sOffA[lr * 72 + f8 * 8] =
            *(const short8v*)&offh[((size_t)b * 4096 + yy * 64 + xx) * 288 +
                                   g * 72 + f8 * 8];
    }
    __syncthreads();

    // ---------------- P0b: S-GEMM (direct store) + geometry ----------------
    {
        short8v a = *(const short8v*)&sQ[wv_ * 16 + row][kb8 * 8];
#pragma unroll
        for (int nt = 0; nt < 5; ++nt) {
            int rr = nt * 16 + row; if (rr > 65) rr = 65;   // tail clamp
            short8v bf = *(const short8v*)&sK[rr][kb8 * 8];
            f32x4 z = {0.f, 0.f, 0.f, 0.f};
            f32x4 d = __builtin_amdgcn_mfma_f32_16x16x32_bf16(a, bf, z, 0, 0, 0);
            int rp = nt * 16 + row;
            if (rp < RPX) {
#pragma unroll
                for (int r = 0; r < 4; ++r)
                    sSW[wv_ * 16 + kb8 * 4 + r][rp] = f2h(d[r]);
            }
        }
    }
    for (int item = tid; item < 576; item += 256) {
        int px = item / 9, pt = item - (item / 9) * 9;
        int lx = px & 15, ly = px >> 4;
        int hup = th * 4 + ly, wup = tw * 16 + lx;
        int lr = (ly >> 1) * 8 + (lx >> 1);
        int ij = ((hup & 1) << 1) | (wup & 1);
        float offy = h2f(sOffA[lr * 72 + pt * 8 + ij]);
        float offx = h2f(sOffA[lr * 72 + pt * 8 + 4 + ij]);
        float py  = offy + hup * 0.5f - 0.25f;
        float pxx = offx + wup * 0.5f - 0.25f;
        float y0f = floorf(py), x0f = floorf(pxx);
        float ty = py - y0f, tx = pxx - x0f;
        int y0 = (int)y0f, x0 = (int)x0f;
        int mk = 0;
        if ((unsigned)y0 < 64u && (unsigned)x0 < 64u)         mk |= 1;
        if ((unsigned)y0 < 64u && (unsigned)(x0+1) < 64u)     mk |= 2;
        if ((unsigned)(y0+1) < 64u && (unsigned)x0 < 64u)     mk |= 4;
        if ((unsigned)(y0+1) < 64u && (unsigned)(x0+1) < 64u) mk |= 8;
        int iy = y0 - ry0, ix = x0 - rx0;
        bool inreg = ((unsigned)iy <= (unsigned)(RROWS - 2)) &&
                     ((unsigned)ix <= (unsigned)(RCOLS - 2));
        int fl, zp;
        if (!mk)        { fl = 16; zp = 0; }
        else if (inreg) { fl = mk | 16; zp = iy * RCOLS + ix; }
        else            { fl = mk; zp = (y0 + 1) * 66 + (x0 + 1); }
        sGt[item] = (uint)f2h(ty) | ((uint)f2h(tx) << 16);
        sGz[item] = (zp << 5) | fl;
    }
    __syncthreads();

    // ---------------- P2: attention logits (overwrites offsets) ------------
    for (int item = tid; item < 576; item += 256) {
        int px = item / 9;
        uint gt = sGt[item];
        float ty = h2f((ushort)gt), tx = h2f((ushort)(gt >> 16));
        int z = sGz[item];
        int fl = z & 31;
        float a;
        if (fl & 16) {
            int zi = z >> 5;
            float w00 = (1.f - ty) * (1.f - tx), w01 = (1.f - ty) * tx;
            float w10 = ty * (1.f - tx), w11 = ty * tx;
            a  = (fl & 1) ? w00 * h2f(sSW[px][zi])             : 0.f;
            a += (fl & 2) ? w01 * h2f(sSW[px][zi + 1])         : 0.f;
            a += (fl & 4) ? w10 * h2f(sSW[px][zi + RCOLS])     : 0.f;
            a += (fl & 8) ? w11 * h2f(sSW[px][zi + RCOLS + 1]) : 0.f;
        } else {
            int t = z >> 5;
            int y0 = t / 66 - 1, x0 = t - (t / 66) * 66 - 1;
            a = 0.f;
#pragma unroll
            for (int c = 0; c < 4; ++c) if ((fl >> c) & 1) {
                int dy = c >> 1, dx = c & 1;
                float wgt = (dy ? ty : 1.f - ty) * (dx ? tx : 1.f - tx);
                const ushort* kr = &kbf[((size_t)b * 4096 + (y0 + dy) * 64 + x0 + dx) * 128 +
                                        g * EMB];
                float dot = 0.f;
                for (int e = 0; e < EMB; ++e) dot += bf2f(sQ[px][e]) * bf2f(kr[e]);
                a += wgt * dot;
            }
            int old = atomicAdd(&sFB[0], 1);
            if (old < 128) sFB[1 + old] = item;
        }
        sAttn[item] = a;
    }
    __syncthreads();

    // ---------------- P3+P4 merged: softmax + zero + W-build (tid<64) ------
    if (tid < 64) {
        int px = tid;
        float aa[NPT];
        float mx = -1e30f;
#pragma unroll
        for (int p = 0; p < NPT; ++p) { aa[p] = sAttn[px * 9 + p]; mx = fmaxf(mx, aa[p]); }
        float s = 0.f;
#pragma unroll
        for (int p = 0; p < NPT; ++p) { aa[p] = __expf(aa[p] - mx); s += aa[p]; }
        float inv = 1.f / s;
#pragma unroll
        for (int p = 0; p < NPT; ++p) { aa[p] *= inv; sAttn[px * 9 + p] = aa[p]; }
        // zero own W row (144 B = 9 x float4, px-private)
        {
            float4 z4 = make_float4(0.f, 0.f, 0.f, 0.f);
            char* wr = (char*)&sSW[px][0];
#pragma unroll
            for (int j = 0; j < 9; ++j) *(float4*)(wr + j * 16) = z4;
        }
        // build W row
#pragma unroll
        for (int pt = 0; pt < NPT; ++pt) {
            int item = px * 9 + pt;
            int z = sGz[item];
            int fl = z & 31;
            if (!(fl & 16)) continue;
            uint gt = sGt[item];
            float ty = h2f((ushort)gt), tx = h2f((ushort)(gt >> 16));
            float a = aa[pt];
            int zi = z >> 5;
            ushort* c = &sSW[px][zi];
            if (fl & 1) c[0]         = f2h(h2f(c[0])         + (1.f-ty)*(1.f-tx)*a);
            if (fl & 2) c[1]         = f2h(h2f(c[1])         + (1.f-ty)*tx*a);
            if (fl & 4) c[RCOLS]     = f2h(h2f(c[RCOLS])     + ty*(1.f-tx)*a);
            if (fl & 8) c[RCOLS + 1] = f2h(h2f(c[RCOLS + 1]) + ty*tx*a);
        }
    }
    __syncthreads();

    // ---------------- P5: O-GEMM (f16 MFMA, K=64) + rp64/65 fix + store ----
    {
        half8v bfm[2][4];
#pragma unroll
        for (int kt = 0; kt < 2; ++kt)
#pragma unroll
            for (int nt = 0; nt < 4; ++nt)
                bfm[kt][nt] = *(const half8v*)&sXt[nt * 16 + row][kt * 32 + kb8 * 8];

        int px = wv_ * 16 + row;
        half8v af0 = *(const half8v*)&sSW[px][kb8 * 8];
        half8v af1 = *(const half8v*)&sSW[px][32 + kb8 * 8];

        f32x4 acc[4];
#pragma unroll
        for (int nt = 0; nt < 4; ++nt) { f32x4 z = {0.f,0.f,0.f,0.f}; acc[nt] = z; }
#pragma unroll
        for (int nt = 0; nt < 4; ++nt) {
            acc[nt] = __builtin_amdgcn_mfma_f32_16x16x32_f16(af0, bfm[0][nt], acc[nt], 0, 0, 0);
            acc[nt] = __builtin_amdgcn_mfma_f32_16x16x32_f16(af1, bfm[1][nt], acc[nt], 0, 0, 0);
        }
        // correction for K columns 64,65 (W cols 64-65 x X cols 64-65)
        float wc[4][2];
#pragma unroll
        for (int r = 0; r < 4; ++r) {
            uint u = *(uint*)&sSW[wv_ * 16 + kb8 * 4 + r][64];
            wc[r][0] = h2f((ushort)u); wc[r][1] = h2f((ushort)(u >> 16));
        }
#pragma unroll
        for (int nt = 0; nt < 4; ++nt) {
            uint u = *(uint*)&sXt[nt * 16 + row][64];
            float x0 = h2f((ushort)u), x1 = h2f((ushort)(u >> 16));
#pragma unroll
            for (int r = 0; r < 4; ++r)
                acc[nt][r] += wc[r][0] * x0 + wc[r][1] * x1;
        }
        int hup = th * 4 + wv_;
#pragma unroll
        for (int nt = 0; nt < 4; ++nt) {
            int ch = nt * 16 + row;
            float* ob = out + ((size_t)b * 256 + g * CGRP + ch) * 16384 +
                        hup * 128 + tw * 16 + kb8 * 4;
#pragma unroll
            for (int r = 0; r < 4; ++r) ob[r] = acc[nt][r];
        }
    }

    // ---------------- P6: rare out-of-region fallback (conditional) --------
    int nfb = min(sFB[0], 128);     // stable since P2 barrier
    if (nfb > 0) {
        __syncthreads();            // uniform: nfb identical across block
        for (int i = 0; i < nfb; ++i) {
            if (tid < 64) {
                int item = sFB[1 + i];
                int px = item / 9;
                uint gt = sGt[item];
                float ty = h2f((ushort)gt), tx = h2f((ushort)(gt >> 16));
                int z = sGz[item];
                float a = sAttn[item];
                int fl = z & 15;
                int t = z >> 5;
                int y0 = t / 66 - 1, x0 = t - (t / 66) * 66 - 1;
                const float* xg = x + ((size_t)b * 256 + g * CGRP + tid) * 4096;
                float v = 0.f;
                if (fl & 1) v += (1.f-ty)*(1.f-tx)*a * xg[y0*64 + x0];
                if (fl & 2) v += (1.f-ty)*tx*a       * xg[y0*64 + x0 + 1];
                if (fl & 4) v += ty*(1.f-tx)*a       * xg[(y0+1)*64 + x0];
                if (fl & 8) v += ty*tx*a             * xg[(y0+1)*64 + x0 + 1];
                int hup = th * 4 + (px >> 4), wup = tw * 16 + (px & 15);
                float* op = out + ((size_t)b * 256 + g * CGRP + tid) * 16384 +
                            hup * 128 + wup;
                *op += v;
            }
        }
    }
}

// ---------------------------------------------------------------------------
extern "C" void kernel_launch(void* const* d_in, const int* in_sizes, int n_in,
                              void* d_out, int out_size, void* d_ws, size_t ws_size,
                              hipStream_t stream)
{
    const float* y    = (const float*)d_in[0];
    const float* x    = (const float*)d_in[1];
    const float* Wq   = (const float*)d_in[2];
    const float* bq   = (const float*)d_in[3];
    const float* Wk   = (const float*)d_in[4];
    const float* bk   = (const float*)d_in[5];
    const float* Woff = (const float*)d_in[6];
    const float* boff = (const float*)d_in[7];
    float* out = (float*)d_out;

    // workspace layout (~15.2 MB total)
    ushort* qbf   = (ushort*)d_ws;                            // 2*16384*128
    ushort* kbf   = qbf + (size_t)B_N * 16384 * 128;          // 2*4096*128
    ushort* offh  = kbf + (size_t)B_N * 4096 * 128;           // 2*4096*288 fp16

    // both convs in one pipelined launch (weights converted in-kernel)
    mfma_gemm<<<dim3(1024), dim3(256), 0, stream>>>(
        y, x, Wq, Wk, Woff, bq, bk, boff, qbf, kbf, offh);

    // fused deformable attention
    deform_kernel<<<dim3(2048), dim3(256), 0, stream>>>(qbf, kbf, offh, x, out);
}

// Round 18
// 60.800 us; speedup vs baseline: 1.2787x; 1.0082x over previous
//
#include <hip/hip_runtime.h>

// Problem constants
#define B_N   2
#define H_LR  64
#define W_LR  64
#define HUP   128
#define WUP   128
#define GRP   4
#define NPT   9
#define EMB   32
#define CGRP  64
#define KIN   256
#define GE    128
#define NOFF  288

typedef __attribute__((ext_vector_type(8))) short short8v;
typedef _Float16 half8v __attribute__((ext_vector_type(8)));
typedef __attribute__((ext_vector_type(4))) float f32x4;

__device__ __forceinline__ ushort f2bf(float f) {
    unsigned u = __float_as_uint(f);
    u += 0x7FFFu + ((u >> 16) & 1u);
    return (ushort)(u >> 16);
}
__device__ __forceinline__ float bf2f(ushort h) {
    return __uint_as_float(((unsigned)h) << 16);
}
__device__ __forceinline__ ushort f2h(float f) {
    _Float16 h = (_Float16)f;
    return __builtin_bit_cast(ushort, h);
}
__device__ __forceinline__ float h2f(ushort u) {
    _Float16 h = __builtin_bit_cast(_Float16, u);
    return (float)h;
}

// ---------------------------------------------------------------------------
// Merged bf16 MFMA GEMM for both 1x1 convs, register-prefetch pipelined.
// (unchanged — frozen since round 15)
// ---------------------------------------------------------------------------
__global__ __launch_bounds__(256, 4) void mfma_gemm(
    const float* __restrict__ y, const float* __restrict__ x,
    const float* __restrict__ Wq, const float* __restrict__ Wk,
    const float* __restrict__ Woff,
    const float* __restrict__ bq, const float* __restrict__ bk,
    const float* __restrict__ boff,
    ushort* __restrict__ qbf, ushort* __restrict__ kbf,
    ushort* __restrict__ offh)
{
    __shared__ __align__(16) ushort sY[64][68];
    __shared__ __align__(16) ushort sB[128][72];

    int bid = blockIdx.x;
    const float* SRC; const float* ba; const float* bb;
    ushort* OBF; ushort* OFH;
    int M, m0, n0, b;
    bool isQ = (bid < 512);
    if (isQ) {
        int mt = bid & 255; b = bid >> 8;
        SRC = y; ba = bq; bb = nullptr; OBF = qbf; OFH = nullptr;
        M = 16384; m0 = mt * 64; n0 = 0;
    } else {
        int r = bid - 512;
        int mt = r & 63, nt2 = (r >> 6) & 3; b = r >> 8;
        SRC = x; ba = bk; bb = boff; OBF = kbf; OFH = offh;
        M = 4096; m0 = mt * 64; n0 = nt2 * 128;
    }

    int tid = threadIdx.x;
    int lane = tid & 63;
    int wv = tid >> 6, wm = wv >> 1, wn = wv & 1;
    int il = lane & 15, g4 = lane >> 4;
    int st_m4 = tid & 15, st_c = tid >> 4;
    int st_c8 = tid & 7,  st_n = tid >> 3;

    const float* wrowp[4];
#pragma unroll
    for (int i = 0; i < 4; ++i) {
        int n = n0 + st_n + i * 32;
        if (isQ)            wrowp[i] = Wq  + (size_t)n * KIN;
        else if (n < GE)    wrowp[i] = Wk  + (size_t)n * KIN;
        else if (n < GE + NOFF) wrowp[i] = Woff + (size_t)(n - GE) * KIN;
        else                wrowp[i] = nullptr;
    }

    f32x4 acc[2][4];
#pragma unroll
    for (int i = 0; i < 2; ++i)
#pragma unroll
        for (int j = 0; j < 4; ++j) { f32x4 z = {0.f,0.f,0.f,0.f}; acc[i][j] = z; }

    const float* src_b = SRC + (size_t)b * KIN * M;

    float4 ra[4]; short8v rb[4];
#pragma unroll
    for (int i = 0; i < 4; ++i)
        ra[i] = *(const float4*)&src_b[(size_t)(st_c + i * 16) * M + m0 + st_m4 * 4];
#pragma unroll
    for (int i = 0; i < 4; ++i) {
        short8v t = {0,0,0,0,0,0,0,0};
        if (wrowp[i]) {
            float4 a = *(const float4*)&wrowp[i][st_c8 * 8];
            float4 c = *(const float4*)&wrowp[i][st_c8 * 8 + 4];
            t[0]=(short)f2bf(a.x); t[1]=(short)f2bf(a.y); t[2]=(short)f2bf(a.z); t[3]=(short)f2bf(a.w);
            t[4]=(short)f2bf(c.x); t[5]=(short)f2bf(c.y); t[6]=(short)f2bf(c.z); t[7]=(short)f2bf(c.w);
        }
        rb[i] = t;
    }

    for (int ks = 0; ks < 4; ++ks) {
#pragma unroll
        for (int i = 0; i < 4; ++i) {
            ushort4 h;
            h.x = f2bf(ra[i].x); h.y = f2bf(ra[i].y);
            h.z = f2bf(ra[i].z); h.w = f2bf(ra[i].w);
            *(ushort4*)&sY[st_c + i * 16][st_m4 * 4] = h;
            *(short8v*)&sB[st_n + i * 32][st_c8 * 8] = rb[i];
        }
        __syncthreads();
        if (ks < 3) {
            int k0 = (ks + 1) * 64;
#pragma unroll
            for (int i = 0; i < 4; ++i)
                ra[i] = *(const float4*)&src_b[(size_t)(k0 + st_c + i * 16) * M + m0 + st_m4 * 4];
#pragma unroll
            for (int i = 0; i < 4; ++i) {
                short8v t = {0,0,0,0,0,0,0,0};
                if (wrowp[i]) {
                    float4 a = *(const float4*)&wrowp[i][k0 + st_c8 * 8];
                    float4 c = *(const float4*)&wrowp[i][k0 + st_c8 * 8 + 4];
                    t[0]=(short)f2bf(a.x); t[1]=(short)f2bf(a.y); t[2]=(short)f2bf(a.z); t[3]=(short)f2bf(a.w);
                    t[4]=(short)f2bf(c.x); t[5]=(short)f2bf(c.y); t[6]=(short)f2bf(c.z); t[7]=(short)f2bf(c.w);
                }
                rb[i] = t;
            }
        }
#pragma unroll
        for (int kc = 0; kc < 2; ++kc) {
            int kb = kc * 32 + g4 * 8;
            short8v af[2], bfr[4];
#pragma unroll
            for (int mf = 0; mf < 2; ++mf) {
                int m = wm * 32 + mf * 16 + il;
                short8v t;
#pragma unroll
                for (int j = 0; j < 8; ++j) t[j] = (short)sY[kb + j][m];
                af[mf] = t;
            }
#pragma unroll
            for (int nf = 0; nf < 4; ++nf)
                bfr[nf] = *(const short8v*)&sB[wn * 64 + nf * 16 + il][kb];
#pragma unroll
            for (int mf = 0; mf < 2; ++mf)
#pragma unroll
                for (int nf = 0; nf < 4; ++nf)
                    acc[mf][nf] = __builtin_amdgcn_mfma_f32_16x16x32_bf16(
                        af[mf], bfr[nf], acc[mf][nf], 0, 0, 0);
        }
        __syncthreads();
    }

#pragma unroll
    for (int mf = 0; mf < 2; ++mf) {
#pragma unroll
        for (int r = 0; r < 4; ++r) {
            int m = m0 + wm * 32 + mf * 16 + g4 * 4 + r;
            size_t row = (size_t)b * M + m;
#pragma unroll
            for (int nf = 0; nf < 4; ++nf) {
                int n = n0 + wn * 64 + nf * 16 + il;
                float v = acc[mf][nf][r];
                if (n < GE) {
                    OBF[row * 128 + n] = f2bf(v + ba[n]);
                } else {
                    int no = n - GE;
                    if (no < NOFF) OFH[row * 288 + no] = f2h(v + bb[no]);
                }
            }
        }
    }
}

// ---------------------------------------------------------------------------
// Fused deformable attention — wave-independent pipeline.
// After the single staging barrier, each wave owns px [16w, 16w+16) and runs
// S-MFMA -> geometry+logits -> softmax -> W-build -> O-GEMM with NO block
// barriers (offsets get a private buffer so nothing cross-wave is clobbered).
// One final barrier guards the rare global fallback pass.
// ---------------------------------------------------------------------------
#define RROWS 6
#define RCOLS 11
#define RPX   66

__global__ __launch_bounds__(256, 4) void deform_kernel(
    const ushort* __restrict__ qbf,  // [B, 16384, 128] bf16 pixel-major
    const ushort* __restrict__ kbf,  // [B, 4096, 128] bf16 pixel-major
    const ushort* __restrict__ offh, // [B, 4096, 288] fp16 pixel-major
    const float* __restrict__ x,     // [B, 256, 64, 64] channel-major (input)
    float* __restrict__ out)         // [B, 256, 128, 128]
{
    __shared__ __align__(16) ushort sXt[64][72];  // x region fp16 [ch][rp 0..65]
    __shared__ __align__(16) ushort sK[66][40];   // k region bf16
    __shared__ __align__(16) ushort sQ[64][40];   // q bf16
    __shared__ __align__(16) ushort sSW[64][72];  // S then W fp16 (wave-private rows)
    __shared__ __align__(16) ushort sOffH[16 * 72]; // offsets fp16 (own buffer)
    __shared__ uint   sGt[576];                   // packed {ty,tx} fp16
    __shared__ int    sGz[576];                   // packed zi + flags
    __shared__ float  sAttn[576];                 // logits -> normalized attn
    __shared__ int    sFB[129];                   // fallback list

    int bxl = blockIdx.x;
    // XCD-aware remap (bijective, 2048 % 8 == 0): XCD k <- one (b,g) pair
    int bx = (bxl & 7) * 256 + (bxl >> 3);
    int tw = bx & 7, th = (bx >> 3) & 31, g = (bx >> 8) & 3, b = bx >> 10;
    int tid = threadIdx.x;
    int wv_ = tid >> 6, lane = tid & 63;
    int row = lane & 15, kb8 = lane >> 4;

    const int ry0 = th * 2 - 2, rx0 = tw * 8 - 1;

    // ---------------- P0a: all staging (coalesced) -------------------------
    if (tid == 0) sFB[0] = 0;
    // x region -> fp16, pair-packed u32 stores
    for (int s = tid; s < 384; s += 256) {
        int gy = s % 6, ch = s / 6;
        int gyg = min(max(ry0 + gy, 0), 63);
        const float* xr = x + ((size_t)b * 256 + g * CGRP + ch) * 4096 + gyg * 64;
        float v[11];
        if (tw >= 1 && tw <= 6) {
            int a0 = rx0 - 3;                    // 16B-aligned, in-bounds
            float tmp[16];
#pragma unroll
            for (int t4 = 0; t4 < 4; ++t4) {
                float4 f = *(const float4*)&xr[a0 + t4 * 4];
                tmp[t4*4+0] = f.x; tmp[t4*4+1] = f.y; tmp[t4*4+2] = f.z; tmp[t4*4+3] = f.w;
            }
#pragma unroll
            for (int qx = 0; qx < RCOLS; ++qx) v[qx] = tmp[qx + 3];
        } else {
#pragma unroll
            for (int qx = 0; qx < RCOLS; ++qx) {
                int gxg = min(max(rx0 + qx, 0), 63);
                v[qx] = xr[gxg];
            }
        }
        ushort* dst = &sXt[ch][0];
        int c0 = gy * RCOLS;
        if (c0 & 1) {
            dst[c0] = f2h(v[0]);
#pragma unroll
            for (int j = 0; j < 5; ++j)
                *(uint*)&dst[c0 + 1 + 2*j] =
                    (uint)f2h(v[1 + 2*j]) | ((uint)f2h(v[2 + 2*j]) << 16);
        } else {
#pragma unroll
            for (int j = 0; j < 5; ++j)
                *(uint*)&dst[c0 + 2*j] =
                    (uint)f2h(v[2*j]) | ((uint)f2h(v[1 + 2*j]) << 16);
            dst[c0 + 10] = f2h(v[10]);
        }
    }
    // k region bf16
    for (int i = tid; i < 264; i += 256) {
        int rp = i >> 2, c4 = i & 3;
        int qy = rp / RCOLS, qx = rp - qy * RCOLS;
        int gy = min(max(ry0 + qy, 0), 63), gx = min(max(rx0 + qx, 0), 63);
        *(short8v*)&sK[rp][c4 * 8] =
            *(const short8v*)&kbf[((size_t)b * 4096 + gy * 64 + gx) * 128 +
                                  g * EMB + c4 * 8];
    }
    // q bf16
    {
        int px = tid >> 2, c4 = tid & 3;
        int hup = th * 4 + (px >> 4), wup = tw * 16 + (px & 15);
        *(short8v*)&sQ[px][c4 * 8] =
            *(const short8v*)&qbf[((size_t)b * 16384 + hup * 128 + wup) * 128 +
                                  g * EMB + c4 * 8];
    }
    // offsets (fp16, coalesced short8v) -> sOffH
    for (int i = tid; i < 144; i += 256) {
        int lr = i / 9, f8 = i - (i / 9) * 9;
        int yy = th * 2 + (lr >> 3), xx = tw * 8 + (lr & 7);
        *(short8v*)&sOffH[lr * 72 + f8 * 8] =
            *(const short8v*)&offh[((size_t)b * 4096 + yy * 64 + xx) * 288 +
                                   g * 72 + f8 * 8];
    }
    __syncthreads();

    // =============== wave-independent pipeline (no block barriers) =========
    // (a) S-GEMM, direct store to own wave's sSW rows
    {
        short8v a = *(const short8v*)&sQ[wv_ * 16 + row][kb8 * 8];
#pragma unroll
        for (int nt = 0; nt < 5; ++nt) {
            int rr = nt * 16 + row; if (rr > 65) rr = 65;   // tail clamp
            short8v bf = *(const short8v*)&sK[rr][kb8 * 8];
            f32x4 z = {0.f, 0.f, 0.f, 0.f};
            f32x4 d = __builtin_amdgcn_mfma_f32_16x16x32_bf16(a, bf, z, 0, 0, 0);
            int rp = nt * 16 + row;
            if (rp < RPX) {
#pragma unroll
                for (int r = 0; r < 4; ++r)
                    sSW[wv_ * 16 + kb8 * 4 + r][rp] = f2h(d[r]);
            }
        }
    }
    __threadfence_block();      // S rows visible to all lanes of this wave

    // (b) geometry + logits for own wave's 144 items
    for (int it = 0; it < 3; ++it) {
        int idx = it * 64 + lane;
        if (idx < 144) {
            int item = wv_ * 144 + idx;
            int px = item / 9, pt = item - px * 9;
            int lx = px & 15, ly = px >> 4;
            int hup = th * 4 + ly, wup = tw * 16 + lx;
            int lr = (ly >> 1) * 8 + (lx >> 1);
            int ij = ((hup & 1) << 1) | (wup & 1);
            float offy = h2f(sOffH[lr * 72 + pt * 8 + ij]);
            float offx = h2f(sOffH[lr * 72 + pt * 8 + 4 + ij]);
            float py  = offy + hup * 0.5f - 0.25f;
            float pxx = offx + wup * 0.5f - 0.25f;
            float y0f = floorf(py), x0f = floorf(pxx);
            float ty = py - y0f, tx = pxx - x0f;
            int y0 = (int)y0f, x0 = (int)x0f;
            int mk = 0;
            if ((unsigned)y0 < 64u && (unsigned)x0 < 64u)         mk |= 1;
            if ((unsigned)y0 < 64u && (unsigned)(x0+1) < 64u)     mk |= 2;
            if ((unsigned)(y0+1) < 64u && (unsigned)x0 < 64u)     mk |= 4;
            if ((unsigned)(y0+1) < 64u && (unsigned)(x0+1) < 64u) mk |= 8;
            int iy = y0 - ry0, ix = x0 - rx0;
            bool inreg = ((unsigned)iy <= (unsigned)(RROWS - 2)) &&
                         ((unsigned)ix <= (unsigned)(RCOLS - 2));
            int fl, zp;
            if (!mk)        { fl = 16; zp = 0; }
            else if (inreg) { fl = mk | 16; zp = iy * RCOLS + ix; }
            else            { fl = mk; zp = (y0 + 1) * 66 + (x0 + 1); }
            sGt[item] = (uint)f2h(ty) | ((uint)f2h(tx) << 16);
            sGz[item] = (zp << 5) | fl;

            float a;
            if (fl & 16) {
                int zi = zp;
                float w00 = (1.f - ty) * (1.f - tx), w01 = (1.f - ty) * tx;
                float w10 = ty * (1.f - tx), w11 = ty * tx;
                a  = (fl & 1) ? w00 * h2f(sSW[px][zi])             : 0.f;
                a += (fl & 2) ? w01 * h2f(sSW[px][zi + 1])         : 0.f;
                a += (fl & 4) ? w10 * h2f(sSW[px][zi + RCOLS])     : 0.f;
                a += (fl & 8) ? w11 * h2f(sSW[px][zi + RCOLS + 1]) : 0.f;
            } else {
                a = 0.f;
#pragma unroll
                for (int c = 0; c < 4; ++c) if ((mk >> c) & 1) {
                    int dy = c >> 1, dx = c & 1;
                    float wgt = (dy ? ty : 1.f - ty) * (dx ? tx : 1.f - tx);
                    const ushort* kr = &kbf[((size_t)b * 4096 + (y0 + dy) * 64 + x0 + dx) * 128 +
                                            g * EMB];
                    float dot = 0.f;
                    for (int e = 0; e < EMB; ++e) dot += bf2f(sQ[px][e]) * bf2f(kr[e]);
                    a += wgt * dot;
                }
                int old = atomicAdd(&sFB[0], 1);
                if (old < 128) sFB[1 + old] = item;
            }
            sAttn[item] = a;
        }
    }
    __threadfence_block();      // logits visible within wave

    // (c) softmax + zero + W-build: lanes 0..15 of each wave, own px
    if (lane < 16) {
        int px = wv_ * 16 + lane;
        float aa[NPT];
        float mx = -1e30f;
#pragma unroll
        for (int p = 0; p < NPT; ++p) { aa[p] = sAttn[px * 9 + p]; mx = fmaxf(mx, aa[p]); }
        float s = 0.f;
#pragma unroll
        for (int p = 0; p < NPT; ++p) { aa[p] = __expf(aa[p] - mx); s += aa[p]; }
        float inv = 1.f / s;
#pragma unroll
        for (int p = 0; p < NPT; ++p) { aa[p] *= inv; sAttn[px * 9 + p] = aa[p]; }
        // zero own W row (144 B = 9 x float4, px-private; overwrites own S row)
        {
            float4 z4 = make_float4(0.f, 0.f, 0.f, 0.f);
            char* wr = (char*)&sSW[px][0];
#pragma unroll
            for (int j = 0; j < 9; ++j) *(float4*)(wr + j * 16) = z4;
        }
        // build W row
#pragma unroll
        for (int pt = 0; pt < NPT; ++pt) {
            int item = px * 9 + pt;
            int z = sGz[item];
            int fl = z & 31;
            if (!(fl & 16)) continue;
            uint gt = sGt[item];
            float ty = h2f((ushort)gt), tx = h2f((ushort)(gt >> 16));
            float a = aa[pt];
            int zi = z >> 5;
            ushort* c = &sSW[px][zi];
            if (fl & 1) c[0]         = f2h(h2f(c[0])         + (1.f-ty)*(1.f-tx)*a);
            if (fl & 2) c[1]         = f2h(h2f(c[1])         + (1.f-ty)*tx*a);
            if (fl & 4) c[RCOLS]     = f2h(h2f(c[RCOLS])     + ty*(1.f-tx)*a);
            if (fl & 8) c[RCOLS + 1] = f2h(h2f(c[RCOLS + 1]) + ty*tx*a);
        }
    }
    __threadfence_block();      // W rows visible within wave

    // (d) O-GEMM (f16 MFMA, K=64) + rp64/65 fix + store
    {
        half8v bfm[2][4];
#pragma unroll
        for (int kt = 0; kt < 2; ++kt)
#pragma unroll
            for (int nt = 0; nt < 4; ++nt)
                bfm[kt][nt] = *(const half8v*)&sXt[nt * 16 + row][kt * 32 + kb8 * 8];

        int px = wv_ * 16 + row;
        half8v af0 = *(const half8v*)&sSW[px][kb8 * 8];
        half8v af1 = *(const half8v*)&sSW[px][32 + kb8 * 8];

        f32x4 acc[4];
#pragma unroll
        for (int nt = 0; nt < 4; ++nt) { f32x4 z = {0.f,0.f,0.f,0.f}; acc[nt] = z; }
#pragma unroll
        for (int nt = 0; nt < 4; ++nt) {
            acc[nt] = __builtin_amdgcn_mfma_f32_16x16x32_f16(af0, bfm[0][nt], acc[nt], 0, 0, 0);
            acc[nt] = __builtin_amdgcn_mfma_f32_16x16x32_f16(af1, bfm[1][nt], acc[nt], 0, 0, 0);
        }
        // correction for K columns 64,65 (W cols 64-65 x X cols 64-65)
        float wc[4][2];
#pragma unroll
        for (int r = 0; r < 4; ++r) {
            uint u = *(uint*)&sSW[wv_ * 16 + kb8 * 4 + r][64];
            wc[r][0] = h2f((ushort)u); wc[r][1] = h2f((ushort)(u >> 16));
        }
#pragma unroll
        for (int nt = 0; nt < 4; ++nt) {
            uint u = *(uint*)&sXt[nt * 16 + row][64];
            float x0 = h2f((ushort)u), x1 = h2f((ushort)(u >> 16));
#pragma unroll
            for (int r = 0; r < 4; ++r)
                acc[nt][r] += wc[r][0] * x0 + wc[r][1] * x1;
        }
        int hup = th * 4 + wv_;
#pragma unroll
        for (int nt = 0; nt < 4; ++nt) {
            int ch = nt * 16 + row;
            float* ob = out + ((size_t)b * 256 + g * CGRP + ch) * 16384 +
                        hup * 128 + tw * 16 + kb8 * 4;
#pragma unroll
            for (int r = 0; r < 4; ++r) ob[r] = acc[nt][r];
        }
    }

    // ---------------- P6: rare out-of-region fallback ----------------------
    __syncthreads();            // makes sFB/sGt/sGz/sAttn stable block-wide
    int nfb = min(sFB[0], 128);
    for (int i = 0; i < nfb; ++i) {
        if (tid < 64) {
            int item = sFB[1 + i];
            int px = item / 9;
            uint gt = sGt[item];
            float ty = h2f((ushort)gt), tx = h2f((ushort)(gt >> 16));
            int z = sGz[item];
            float a = sAttn[item];
            int fl = z & 15;
            int t = z >> 5;
            int y0 = t / 66 - 1, x0 = t - (t / 66) * 66 - 1;
            const float* xg = x + ((size_t)b * 256 + g * CGRP + tid) * 4096;
            float v = 0.f;
            if (fl & 1) v += (1.f-ty)*(1.f-tx)*a * xg[y0*64 + x0];
            if (fl & 2) v += (1.f-ty)*tx*a       * xg[y0*64 + x0 + 1];
            if (fl & 4) v += ty*(1.f-tx)*a       * xg[(y0+1)*64 + x0];
            if (fl & 8) v += ty*tx*a             * xg[(y0+1)*64 + x0 + 1];
            int hup = th * 4 + (px >> 4), wup = tw * 16 + (px & 15);
            float* op = out + ((size_t)b * 256 + g * CGRP + tid) * 16384 +
                        hup * 128 + wup;
            *op += v;
        }
    }
}

// ---------------------------------------------------------------------------
extern "C" void kernel_launch(void* const* d_in, const int* in_sizes, int n_in,
                              void* d_out, int out_size, void* d_ws, size_t ws_size,
                              hipStream_t stream)
{
    const float* y    = (const float*)d_in[0];
    const float* x    = (const float*)d_in[1];
    const float* Wq   = (const float*)d_in[2];
    const float* bq   = (const float*)d_in[3];
    const float* Wk   = (const float*)d_in[4];
    const float* bk   = (const float*)d_in[5];
    const float* Woff = (const float*)d_in[6];
    const float* boff = (const float*)d_in[7];
    float* out = (float*)d_out;

    // workspace layout (~15.2 MB total)
    ushort* qbf   = (ushort*)d_ws;                            // 2*16384*128
    ushort* kbf   = qbf + (size_t)B_N * 16384 * 128;          // 2*4096*128
    ushort* offh  = kbf + (size_t)B_N * 4096 * 128;           // 2*4096*288 fp16

    // both convs in one pipelined launch (weights converted in-kernel)
    mfma_gemm<<<dim3(1024), dim3(256), 0, stream>>>(
        y, x, Wq, Wk, Woff, bq, bk, boff, qbf, kbf, offh);

    // fused deformable attention
    deform_kernel<<<dim3(2048), dim3(256), 0, stream>>>(qbf, kbf, offh, x, out);
}